// Round 1
// baseline (606.346 us; speedup 1.0000x reference)
//
#include <hip/hip_runtime.h>
#include <hip/hip_bf16.h>
#include <math.h>

#define NEGV -1000000000.0f

__device__ __forceinline__ float sigf(float x){ return 1.0f/(1.0f+expf(-x)); }

// ---------------------------------------------------------------- prep weights
// Pack Whh (1024x256, row-major gate x k) into bf16 pairs laid out [k2][gate]:
// wT[k2*1024+g] = (Whh[g][2k2], Whh[g][2k2+1]).  Also bias = bih+bhh per dir.
__global__ void prep_weights(const float* __restrict__ Whh_f, const float* __restrict__ Whh_b,
                             const float* __restrict__ bih_f, const float* __restrict__ bhh_f,
                             const float* __restrict__ bih_b, const float* __restrict__ bhh_b,
                             __hip_bfloat162* __restrict__ wTf, __hip_bfloat162* __restrict__ wTb,
                             float* __restrict__ biasf, float* __restrict__ biasb) {
    int idx = blockIdx.x * blockDim.x + threadIdx.x;      // 0 .. 262143
    if (idx < 262144) {
        int dir = idx >> 17;
        int r   = idx & 131071;
        int k2  = r >> 10;
        int g   = r & 1023;
        const float* W = dir ? Whh_b : Whh_f;
        __hip_bfloat162 t;
        t.x = __float2bfloat16(W[g*256 + 2*k2]);
        t.y = __float2bfloat16(W[g*256 + 2*k2 + 1]);
        (dir ? wTb : wTf)[r] = t;
    }
    if (idx < 1024)       biasf[idx]      = bih_f[idx]      + bhh_f[idx];
    else if (idx < 2048)  biasb[idx-1024] = bih_b[idx-1024] + bhh_b[idx-1024];
}

// ---------------------------------------------------------------- embed mean
// embeds[b*64+l][d] = sum_w emb[sents[b,l,w]][d]*mask / (elen + (elen==0))
__global__ __launch_bounds__(256) void embed_mean(const int* __restrict__ sents,
                                                  const float* __restrict__ mask,
                                                  const float* __restrict__ emb,
                                                  float* __restrict__ embeds) {
    int bl = blockIdx.x;          // 0..511
    int d  = threadIdx.x;         // 0..255
    const int*   srow = sents + bl*32;
    const float* mrow = mask  + bl*32;
    float acc = 0.0f, el = 0.0f;
    for (int w = 0; w < 32; ++w) {
        float m = mrow[w];
        el  += m;
        acc += emb[(size_t)srow[w]*256 + d] * m;
    }
    float den = el + (el == 0.0f ? 1.0f : 0.0f);
    embeds[bl*256 + d] = acc / den;
}

// ---------------------------------------------------------------- tiled GEMM
// C[m][n] = sum_k A[m][k]*B[n][k] + bias[n]   (B row-major [N][K])
// 32x32 tile, 256 threads, 2x2 micro-tile, optional batch (blockIdx.z).
__global__ __launch_bounds__(256) void gemm32(const float* __restrict__ A,
                                              const float* __restrict__ Bm,
                                              const float* __restrict__ bias,
                                              float* __restrict__ C,
                                              int N, int K, int sA, int sB, int sC) {
    A  += (size_t)blockIdx.z * sA;
    Bm += (size_t)blockIdx.z * sB;
    C  += (size_t)blockIdx.z * sC;
    __shared__ float As[32][33];   // [k][m]
    __shared__ float Bs[32][33];   // [k][n]
    int tid = threadIdx.x;
    int tx = tid & 15, ty = tid >> 4;
    int row0 = blockIdx.x * 32, col0 = blockIdx.y * 32;
    float a00=0.f, a01=0.f, a10=0.f, a11=0.f;
    int e = tid * 4;
    int lr = e >> 5, lc = e & 31;
    for (int k0 = 0; k0 < K; k0 += 32) {
        const float* ap = A  + (size_t)(row0+lr)*K + k0 + lc;
        const float* bp = Bm + (size_t)(col0+lr)*K + k0 + lc;
        As[lc  ][lr] = ap[0]; As[lc+1][lr] = ap[1]; As[lc+2][lr] = ap[2]; As[lc+3][lr] = ap[3];
        Bs[lc  ][lr] = bp[0]; Bs[lc+1][lr] = bp[1]; Bs[lc+2][lr] = bp[2]; Bs[lc+3][lr] = bp[3];
        __syncthreads();
        #pragma unroll
        for (int kc = 0; kc < 32; ++kc) {
            float x0 = As[kc][ty*2], x1 = As[kc][ty*2+1];
            float y0 = Bs[kc][tx*2], y1 = Bs[kc][tx*2+1];
            a00 = fmaf(x0,y0,a00); a01 = fmaf(x0,y1,a01);
            a10 = fmaf(x1,y0,a10); a11 = fmaf(x1,y1,a11);
        }
        __syncthreads();
    }
    int rr = row0 + ty*2, cc = col0 + tx*2;
    float b0 = bias ? bias[cc]   : 0.0f;
    float b1 = bias ? bias[cc+1] : 0.0f;
    C[(size_t)rr*N + cc]       = a00 + b0;
    C[(size_t)rr*N + cc + 1]   = a01 + b1;
    C[(size_t)(rr+1)*N + cc]   = a10 + b0;
    C[(size_t)(rr+1)*N + cc+1] = a11 + b1;
}

// ---------------------------------------------------------------- LSTM recurrence
// 8 steps over the B axis; 64 positions are independent batch lanes.
// Block = (dir, position-pair). Thread j owns cell j for both positions.
__global__ __launch_bounds__(256) void lstm_rec(const float* __restrict__ gxf,
                                                const float* __restrict__ gxb,
                                                const __hip_bfloat162* __restrict__ wTf,
                                                const __hip_bfloat162* __restrict__ wTb,
                                                float* __restrict__ hall) {
    int blk  = blockIdx.x;        // 0..63
    int dir  = blk >> 5;
    int pair = blk & 31;
    int p0 = pair*2, p1 = p0 + 1;
    int j  = threadIdx.x;         // cell 0..255
    const float* gx = dir ? gxb : gxf;
    const __hip_bfloat162* wT = dir ? wTb : wTf;
    __shared__ float h0s[256], h1s[256];
    h0s[j] = 0.0f; h1s[j] = 0.0f;
    float c0 = 0.0f, c1 = 0.0f;
    __syncthreads();
    for (int s = 0; s < 8; ++s) {
        int t = dir ? (7 - s) : s;
        const float* g0 = gx + (size_t)(t*64 + p0)*1024;
        const float* g1 = gx + (size_t)(t*64 + p1)*1024;
        float ai0 = g0[j], af0 = g0[256+j], ag0 = g0[512+j], ao0 = g0[768+j];
        float ai1 = g1[j], af1 = g1[256+j], ag1 = g1[512+j], ao1 = g1[768+j];
        for (int k2 = 0; k2 < 128; ++k2) {
            const __hip_bfloat162* wrow = wT + k2*1024 + j;
            float2 wi = __bfloat1622float2(wrow[0]);
            float2 wf = __bfloat1622float2(wrow[256]);
            float2 wg = __bfloat1622float2(wrow[512]);
            float2 wo = __bfloat1622float2(wrow[768]);
            float ha = h0s[2*k2], hb = h0s[2*k2+1];
            float hc = h1s[2*k2], hd = h1s[2*k2+1];
            ai0 = fmaf(wi.x,ha, fmaf(wi.y,hb, ai0));
            af0 = fmaf(wf.x,ha, fmaf(wf.y,hb, af0));
            ag0 = fmaf(wg.x,ha, fmaf(wg.y,hb, ag0));
            ao0 = fmaf(wo.x,ha, fmaf(wo.y,hb, ao0));
            ai1 = fmaf(wi.x,hc, fmaf(wi.y,hd, ai1));
            af1 = fmaf(wf.x,hc, fmaf(wf.y,hd, af1));
            ag1 = fmaf(wg.x,hc, fmaf(wg.y,hd, ag1));
            ao1 = fmaf(wo.x,hc, fmaf(wo.y,hd, ao1));
        }
        __syncthreads();   // everyone done reading h0s/h1s
        c0 = sigf(af0)*c0 + sigf(ai0)*tanhf(ag0);
        float h0 = sigf(ao0)*tanhf(c0);
        c1 = sigf(af1)*c1 + sigf(ai1)*tanhf(ag1);
        float h1 = sigf(ao1)*tanhf(c1);
        h0s[j] = h0; h1s[j] = h1;
        hall[(size_t)(t*64 + p0)*512 + dir*256 + j] = h0;
        hall[(size_t)(t*64 + p1)*512 + dir*256 + j] = h1;
        __syncthreads();   // h visible before next step's reads
    }
}

// ---------------------------------------------------------------- u/v projections
// trio[b,i] = [h[b,i], h[b,i-1]|0, h[b,i+1]|0];  u = trio . Ws[0:1536], v = trio . Ws[1536:3072]
__global__ __launch_bounds__(256) void uv_kernel(const float* __restrict__ hall,
                                                 const float* __restrict__ Ws,
                                                 float* __restrict__ u, float* __restrict__ v) {
    int bi = blockIdx.x;                 // 0..511  (= b*64+i)
    int i  = bi & 63;
    int tid = threadIdx.x;
    float pu = 0.0f, pv = 0.0f;
    for (int q = tid; q < 1536; q += 256) {
        int seg = q >> 9, kk = q & 511;
        float tv = 0.0f;
        if (seg == 0)            tv = hall[(size_t)bi*512 + kk];
        else if (seg == 1)       { if (i > 0)  tv = hall[(size_t)(bi-1)*512 + kk]; }
        else                     { if (i < 63) tv = hall[(size_t)(bi+1)*512 + kk]; }
        pu = fmaf(tv, Ws[q],        pu);
        pv = fmaf(tv, Ws[1536 + q], pv);
    }
    for (int off = 32; off; off >>= 1) { pu += __shfl_xor(pu, off); pv += __shfl_xor(pv, off); }
    __shared__ float ru[4], rv[4];
    int wv = tid >> 6, lane = tid & 63;
    if (lane == 0) { ru[wv] = pu; rv[wv] = pv; }
    __syncthreads();
    if (tid == 0) { u[bi] = ru[0]+ru[1]+ru[2]+ru[3]; v[bi] = rv[0]+rv[1]+rv[2]+rv[3]; }
}

// ---------------------------------------------------------------- row logsumexp of S
__global__ __launch_bounds__(256) void row_lse(const float* __restrict__ S, float* __restrict__ lseS) {
    int b = blockIdx.x;
    int wv = threadIdx.x >> 6, lane = threadIdx.x & 63;
    for (int i = wv; i < 64; i += 4) {
        float x = S[(size_t)(b*64 + i)*64 + lane];
        float m = x;
        for (int off = 32; off; off >>= 1) m = fmaxf(m, __shfl_xor(m, off));
        float se = expf(x - m);
        for (int off = 32; off; off >>= 1) se += __shfl_xor(se, off);
        if (lane == 0) lseS[b*64 + i] = m + logf(se);
    }
}

// ---------------------------------------------------------------- Eisner inside (log partition)
// One block per batch. Two LDS buffers, 64x65 padded:
//   bufR upper+diag = C_r[i][j];  bufR lower = I_r[i][j] stored at [j][i]
//   bufL upper+diag = C_l[i][j];  bufL lower = I_l[i][j] stored at [j][i]
__global__ __launch_bounds__(1024) void eisner(const float* __restrict__ u,
                                               const float* __restrict__ v,
                                               const float* __restrict__ bs,
                                               float* __restrict__ logZ) {
    int b = blockIdx.x;
    __shared__ float bufR[64][65];
    __shared__ float bufL[64][65];
    __shared__ float su[64], sv[64];
    int tid = threadIdx.x;
    if (tid < 64) { su[tid] = u[b*64 + tid]; sv[tid] = v[b*64 + tid]; }
    float bsv = bs[0];
    for (int e = tid; e < 64*65; e += 1024) {
        int i = e / 65, jj = e % 65;
        float val = (i == jj) ? 0.0f : NEGV;
        bufR[i][jj] = val; bufL[i][jj] = val;
    }
    __syncthreads();
    int wv = tid >> 6, lane = tid & 63;
    for (int w = 1; w < 64; ++w) {
        int ns = 64 - w;
        // Phase A: incomplete spans
        for (int i = wv; i < ns; i += 16) {
            int j = i + w;
            float va = -INFINITY;
            if (lane < w) va = bufR[i][i + lane] + bufL[i + lane + 1][j];
            float m = va;
            for (int off = 32; off; off >>= 1) m = fmaxf(m, __shfl_xor(m, off));
            float se = (lane < w) ? expf(va - m) : 0.0f;
            for (int off = 32; off; off >>= 1) se += __shfl_xor(se, off);
            float inc = m + logf(se);
            if (lane == 0) {
                bufR[j][i] = inc + su[i] + sv[j] + bsv;   // I_r[i][j] (s[i][j])
                bufL[j][i] = inc + su[j] + sv[i] + bsv;   // I_l[i][j] (s[j][i])
            }
        }
        __syncthreads();
        // Phase B: complete spans
        for (int i = wv; i < ns; i += 16) {
            int j = i + w;
            float vr = -INFINITY, vl = -INFINITY;
            if (lane < w) {
                int k  = i + 1 + lane;   // I_r[i][k] + C_r[k][j]
                vr = bufR[k][i] + bufR[k][j];
                int k2 = i + lane;       // C_l[i][k] + I_l[k][j]
                vl = bufL[i][k2] + bufL[j][k2];
            }
            float mr = vr;
            for (int off = 32; off; off >>= 1) mr = fmaxf(mr, __shfl_xor(mr, off));
            float ser = (lane < w) ? expf(vr - mr) : 0.0f;
            for (int off = 32; off; off >>= 1) ser += __shfl_xor(ser, off);
            float ml = vl;
            for (int off = 32; off; off >>= 1) ml = fmaxf(ml, __shfl_xor(ml, off));
            float sel = (lane < w) ? expf(vl - ml) : 0.0f;
            for (int off = 32; off; off >>= 1) sel += __shfl_xor(sel, off);
            if (lane == 0) {
                bufR[i][j] = mr + logf(ser);   // C_r[i][j]
                bufL[i][j] = ml + logf(sel);   // C_l[i][j]
            }
        }
        __syncthreads();
    }
    if (tid == 0) logZ[b] = bufR[0][63];
}

// ---------------------------------------------------------------- final loss
__global__ __launch_bounds__(512) void finalize(const float* __restrict__ u,
                                                const float* __restrict__ v,
                                                const float* __restrict__ bs,
                                                const float* __restrict__ S,
                                                const float* __restrict__ lseS,
                                                const float* __restrict__ prior,
                                                const int* __restrict__ heads,
                                                const float* __restrict__ logZ,
                                                float* __restrict__ out) {
    int b = threadIdx.x >> 6;      // 8 waves, one per batch
    int m = threadIdx.x & 63;
    __shared__ float red[8];
    float gv = -INFINITY;
    if (m >= 1) {
        int hd = heads[b*64 + m];
        float crf = u[b*64 + hd] + v[b*64 + m] + bs[0];
        float rec = S[(size_t)(b*64 + hd)*64 + m] - lseS[b*64 + hd];
        gv = crf + rec + prior[(size_t)(b*64 + hd)*64 + m] * (1.0f/64.0f);
    }
    float mm = gv;
    for (int off = 32; off; off >>= 1) mm = fmaxf(mm, __shfl_xor(mm, off));
    float se = (m >= 1) ? expf(gv - mm) : 0.0f;
    for (int off = 32; off; off >>= 1) se += __shfl_xor(se, off);
    if (m == 0) red[b] = (mm + logf(se)) - logZ[b];
    __syncthreads();
    if (threadIdx.x == 0) {
        float a = 0.0f;
        for (int q = 0; q < 8; ++q) a += red[q];
        out[0] = -(a / 8.0f);
    }
}

// ---------------------------------------------------------------- launch
extern "C" void kernel_launch(void* const* d_in, const int* in_sizes, int n_in,
                              void* d_out, int out_size, void* d_ws, size_t ws_size,
                              hipStream_t stream) {
    const int*   sents = (const int*)  d_in[0];
    const float* mask  = (const float*)d_in[1];
    const float* prior = (const float*)d_in[2];
    const int*   heads = (const int*)  d_in[3];
    const float* emb   = (const float*)d_in[4];
    const float* Wih_f = (const float*)d_in[5];
    const float* Whh_f = (const float*)d_in[6];
    const float* bih_f = (const float*)d_in[7];
    const float* bhh_f = (const float*)d_in[8];
    const float* Wih_b = (const float*)d_in[9];
    const float* Whh_b = (const float*)d_in[10];
    const float* bih_b = (const float*)d_in[11];
    const float* bhh_b = (const float*)d_in[12];
    const float* W1    = (const float*)d_in[13];
    const float* b1    = (const float*)d_in[14];
    const float* W2    = (const float*)d_in[15];
    const float* b2    = (const float*)d_in[16];
    const float* Ws    = (const float*)d_in[17];
    const float* bs    = (const float*)d_in[18];
    float* out = (float*)d_out;

    char* w = (char*)d_ws;
    float* embeds = (float*)(w + 0);                    // 512*256        = 512 KB
    float* gxf    = (float*)(w + 524288);               // 512*1024       = 2 MB
    float* gxb    = (float*)(w + 2621440);              // 2 MB
    __hip_bfloat162* wTf = (__hip_bfloat162*)(w + 4718592);  // 512 KB
    __hip_bfloat162* wTb = (__hip_bfloat162*)(w + 5242880);  // 512 KB
    float* biasf  = (float*)(w + 5767168);              // 4 KB
    float* biasb  = (float*)(w + 5771264);              // 4 KB
    float* hall   = (float*)(w + 5775360);              // 512*512        = 1 MB
    float* uArr   = (float*)(w + 6823936);              // 2 KB
    float* vArr   = (float*)(w + 6825984);              // 2 KB
    float* p1     = (float*)(w + 6828032);              // 512*128        = 256 KB
    float* p2     = (float*)(w + 7090176);              // 256 KB
    float* S      = (float*)(w + 7352320);              // 8*64*64        = 128 KB
    float* lseS   = (float*)(w + 7483392);              // 2 KB
    float* logZ   = (float*)(w + 7485440);              // 32 B

    prep_weights<<<1024, 256, 0, stream>>>(Whh_f, Whh_b, bih_f, bhh_f, bih_b, bhh_b,
                                           wTf, wTb, biasf, biasb);
    embed_mean<<<512, 256, 0, stream>>>(sents, mask, emb, embeds);
    // gx = embeds @ Wih^T + (bih+bhh), per direction:  M=512, N=1024, K=256
    gemm32<<<dim3(16,32,1), 256, 0, stream>>>(embeds, Wih_f, biasf, gxf, 1024, 256, 0,0,0);
    gemm32<<<dim3(16,32,1), 256, 0, stream>>>(embeds, Wih_b, biasb, gxb, 1024, 256, 0,0,0);
    lstm_rec<<<64, 256, 0, stream>>>(gxf, gxb, wTf, wTb, hall);
    uv_kernel<<<512, 256, 0, stream>>>(hall, Ws, uArr, vArr);
    // p1 = hall @ W1^T + b1 ; p2 = hall @ W2^T + b2 :  M=512, N=128, K=512
    gemm32<<<dim3(16,4,1), 256, 0, stream>>>(hall, W1, b1, p1, 128, 512, 0,0,0);
    gemm32<<<dim3(16,4,1), 256, 0, stream>>>(hall, W2, b2, p2, 128, 512, 0,0,0);
    // S[b] = p1[b] @ p2[b]^T : batched M=64, N=64, K=128
    gemm32<<<dim3(2,2,8), 256, 0, stream>>>(p1, p2, nullptr, S, 64, 128, 8192, 8192, 4096);
    row_lse<<<8, 256, 0, stream>>>(S, lseS);
    eisner<<<8, 1024, 0, stream>>>(uArr, vArr, bs, logZ);
    finalize<<<1, 512, 0, stream>>>(uArr, vArr, bs, S, lseS, prior, heads, logZ, out);
    (void)in_sizes; (void)n_in; (void)out_size; (void)ws_size;
}

// Round 2
// 560.524 us; speedup vs baseline: 1.0817x; 1.0817x over previous
//
#include <hip/hip_runtime.h>
#include <hip/hip_bf16.h>
#include <math.h>

#define NEGV -1000000000.0f

__device__ __forceinline__ float sigf(float x){ return 1.0f/(1.0f+expf(-x)); }

// ---------------------------------------------------------------- prep weights
__global__ void prep_weights(const float* __restrict__ Whh_f, const float* __restrict__ Whh_b,
                             const float* __restrict__ bih_f, const float* __restrict__ bhh_f,
                             const float* __restrict__ bih_b, const float* __restrict__ bhh_b,
                             __hip_bfloat162* __restrict__ wTf, __hip_bfloat162* __restrict__ wTb,
                             float* __restrict__ biasf, float* __restrict__ biasb) {
    int idx = blockIdx.x * blockDim.x + threadIdx.x;      // 0 .. 262143
    if (idx < 262144) {
        int dir = idx >> 17;
        int r   = idx & 131071;
        int k2  = r >> 10;
        int g   = r & 1023;
        const float* W = dir ? Whh_b : Whh_f;
        __hip_bfloat162 t;
        t.x = __float2bfloat16(W[g*256 + 2*k2]);
        t.y = __float2bfloat16(W[g*256 + 2*k2 + 1]);
        (dir ? wTb : wTf)[r] = t;
    }
    if (idx < 1024)       biasf[idx]      = bih_f[idx]      + bhh_f[idx];
    else if (idx < 2048)  biasb[idx-1024] = bih_b[idx-1024] + bhh_b[idx-1024];
}

// ---------------------------------------------------------------- embed mean
__global__ __launch_bounds__(256) void embed_mean(const int* __restrict__ sents,
                                                  const float* __restrict__ mask,
                                                  const float* __restrict__ emb,
                                                  float* __restrict__ embeds) {
    int bl = blockIdx.x;          // 0..511
    int d  = threadIdx.x;         // 0..255
    const int*   srow = sents + bl*32;
    const float* mrow = mask  + bl*32;
    float acc = 0.0f, el = 0.0f;
    for (int w = 0; w < 32; ++w) {
        float m = mrow[w];
        el  += m;
        acc += emb[(size_t)srow[w]*256 + d] * m;
    }
    float den = el + (el == 0.0f ? 1.0f : 0.0f);
    embeds[bl*256 + d] = acc / den;
}

// ---------------------------------------------------------------- tiled GEMM
__global__ __launch_bounds__(256) void gemm32(const float* __restrict__ A,
                                              const float* __restrict__ Bm,
                                              const float* __restrict__ bias,
                                              float* __restrict__ C,
                                              int N, int K, int sA, int sB, int sC) {
    A  += (size_t)blockIdx.z * sA;
    Bm += (size_t)blockIdx.z * sB;
    C  += (size_t)blockIdx.z * sC;
    __shared__ float As[32][33];   // [k][m]
    __shared__ float Bs[32][33];   // [k][n]
    int tid = threadIdx.x;
    int tx = tid & 15, ty = tid >> 4;
    int row0 = blockIdx.x * 32, col0 = blockIdx.y * 32;
    float a00=0.f, a01=0.f, a10=0.f, a11=0.f;
    int e = tid * 4;
    int lr = e >> 5, lc = e & 31;
    for (int k0 = 0; k0 < K; k0 += 32) {
        const float* ap = A  + (size_t)(row0+lr)*K + k0 + lc;
        const float* bp = Bm + (size_t)(col0+lr)*K + k0 + lc;
        As[lc  ][lr] = ap[0]; As[lc+1][lr] = ap[1]; As[lc+2][lr] = ap[2]; As[lc+3][lr] = ap[3];
        Bs[lc  ][lr] = bp[0]; Bs[lc+1][lr] = bp[1]; Bs[lc+2][lr] = bp[2]; Bs[lc+3][lr] = bp[3];
        __syncthreads();
        #pragma unroll
        for (int kc = 0; kc < 32; ++kc) {
            float x0 = As[kc][ty*2], x1 = As[kc][ty*2+1];
            float y0 = Bs[kc][tx*2], y1 = Bs[kc][tx*2+1];
            a00 = fmaf(x0,y0,a00); a01 = fmaf(x0,y1,a01);
            a10 = fmaf(x1,y0,a10); a11 = fmaf(x1,y1,a11);
        }
        __syncthreads();
    }
    int rr = row0 + ty*2, cc = col0 + tx*2;
    float b0 = bias ? bias[cc]   : 0.0f;
    float b1 = bias ? bias[cc+1] : 0.0f;
    C[(size_t)rr*N + cc]       = a00 + b0;
    C[(size_t)rr*N + cc + 1]   = a01 + b1;
    C[(size_t)(rr+1)*N + cc]   = a10 + b0;
    C[(size_t)(rr+1)*N + cc+1] = a11 + b1;
}

// ---------------------------------------------------------------- LSTM recurrence
__global__ __launch_bounds__(256) void lstm_rec(const float* __restrict__ gxf,
                                                const float* __restrict__ gxb,
                                                const __hip_bfloat162* __restrict__ wTf,
                                                const __hip_bfloat162* __restrict__ wTb,
                                                float* __restrict__ hall) {
    int blk  = blockIdx.x;        // 0..63
    int dir  = blk >> 5;
    int pair = blk & 31;
    int p0 = pair*2, p1 = p0 + 1;
    int j  = threadIdx.x;         // cell 0..255
    const float* gx = dir ? gxb : gxf;
    const __hip_bfloat162* wT = dir ? wTb : wTf;
    __shared__ float h0s[256], h1s[256];
    h0s[j] = 0.0f; h1s[j] = 0.0f;
    float c0 = 0.0f, c1 = 0.0f;
    __syncthreads();
    for (int s = 0; s < 8; ++s) {
        int t = dir ? (7 - s) : s;
        const float* g0 = gx + (size_t)(t*64 + p0)*1024;
        const float* g1 = gx + (size_t)(t*64 + p1)*1024;
        float ai0 = g0[j], af0 = g0[256+j], ag0 = g0[512+j], ao0 = g0[768+j];
        float ai1 = g1[j], af1 = g1[256+j], ag1 = g1[512+j], ao1 = g1[768+j];
        for (int k2 = 0; k2 < 128; ++k2) {
            const __hip_bfloat162* wrow = wT + k2*1024 + j;
            float2 wi = __bfloat1622float2(wrow[0]);
            float2 wf = __bfloat1622float2(wrow[256]);
            float2 wg = __bfloat1622float2(wrow[512]);
            float2 wo = __bfloat1622float2(wrow[768]);
            float ha = h0s[2*k2], hb = h0s[2*k2+1];
            float hc = h1s[2*k2], hd = h1s[2*k2+1];
            ai0 = fmaf(wi.x,ha, fmaf(wi.y,hb, ai0));
            af0 = fmaf(wf.x,ha, fmaf(wf.y,hb, af0));
            ag0 = fmaf(wg.x,ha, fmaf(wg.y,hb, ag0));
            ao0 = fmaf(wo.x,ha, fmaf(wo.y,hb, ao0));
            ai1 = fmaf(wi.x,hc, fmaf(wi.y,hd, ai1));
            af1 = fmaf(wf.x,hc, fmaf(wf.y,hd, af1));
            ag1 = fmaf(wg.x,hc, fmaf(wg.y,hd, ag1));
            ao1 = fmaf(wo.x,hc, fmaf(wo.y,hd, ao1));
        }
        __syncthreads();
        c0 = sigf(af0)*c0 + sigf(ai0)*tanhf(ag0);
        float h0 = sigf(ao0)*tanhf(c0);
        c1 = sigf(af1)*c1 + sigf(ai1)*tanhf(ag1);
        float h1 = sigf(ao1)*tanhf(c1);
        h0s[j] = h0; h1s[j] = h1;
        hall[(size_t)(t*64 + p0)*512 + dir*256 + j] = h0;
        hall[(size_t)(t*64 + p1)*512 + dir*256 + j] = h1;
        __syncthreads();
    }
}

// ---------------------------------------------------------------- u/v projections
__global__ __launch_bounds__(256) void uv_kernel(const float* __restrict__ hall,
                                                 const float* __restrict__ Ws,
                                                 float* __restrict__ u, float* __restrict__ v) {
    int bi = blockIdx.x;                 // 0..511  (= b*64+i)
    int i  = bi & 63;
    int tid = threadIdx.x;
    float pu = 0.0f, pv = 0.0f;
    for (int q = tid; q < 1536; q += 256) {
        int seg = q >> 9, kk = q & 511;
        float tv = 0.0f;
        if (seg == 0)            tv = hall[(size_t)bi*512 + kk];
        else if (seg == 1)       { if (i > 0)  tv = hall[(size_t)(bi-1)*512 + kk]; }
        else                     { if (i < 63) tv = hall[(size_t)(bi+1)*512 + kk]; }
        pu = fmaf(tv, Ws[q],        pu);
        pv = fmaf(tv, Ws[1536 + q], pv);
    }
    for (int off = 32; off; off >>= 1) { pu += __shfl_xor(pu, off); pv += __shfl_xor(pv, off); }
    __shared__ float ru[4], rv[4];
    int wv = tid >> 6, lane = tid & 63;
    if (lane == 0) { ru[wv] = pu; rv[wv] = pv; }
    __syncthreads();
    if (tid == 0) { u[bi] = ru[0]+ru[1]+ru[2]+ru[3]; v[bi] = rv[0]+rv[1]+rv[2]+rv[3]; }
}

// ---------------------------------------------------------------- row logsumexp of S
__global__ __launch_bounds__(256) void row_lse(const float* __restrict__ S, float* __restrict__ lseS) {
    int b = blockIdx.x;
    int wv = threadIdx.x >> 6, lane = threadIdx.x & 63;
    for (int i = wv; i < 64; i += 4) {
        float x = S[(size_t)(b*64 + i)*64 + lane];
        float m = x;
        for (int off = 32; off; off >>= 1) m = fmaxf(m, __shfl_xor(m, off));
        float se = expf(x - m);
        for (int off = 32; off; off >>= 1) se += __shfl_xor(se, off);
        if (lane == 0) lseS[b*64 + i] = m + logf(se);
    }
}

// ---------------------------------------------------------------- Eisner inside (log partition)
// One block per batch, 1024 threads (16 waves).
// Lane-packed spans: width w uses g = pow2ceil(w) lanes per span, so a wave
// handles 64/g spans IN PARALLEL (reduce depth log2 g, not 6), and the <=2
// remaining serial span-slots are unrolled with interleaved shuffle chains.
//   bufR upper+diag = C_r[i][j];  bufR lower [j][i] = I_r[i][j]
//   bufL upper+diag = C_l[i][j];  bufL lower [j][i] = I_l[i][j]
__global__ __launch_bounds__(1024) void eisner(const float* __restrict__ u,
                                               const float* __restrict__ v,
                                               const float* __restrict__ bs,
                                               float* __restrict__ logZ) {
    int b = blockIdx.x;
    __shared__ float bufR[64][65];
    __shared__ float bufL[64][65];
    __shared__ float su[64], sv[64];
    int tid = threadIdx.x;
    if (tid < 64) { su[tid] = u[b*64 + tid]; sv[tid] = v[b*64 + tid]; }
    float bsv = bs[0];
    for (int e = tid; e < 64*65; e += 1024) {
        int i = e / 65, jj = e % 65;
        float val = (i == jj) ? 0.0f : NEGV;
        bufR[i][jj] = val; bufL[i][jj] = val;
    }
    __syncthreads();
    int wv = tid >> 6, lane = tid & 63;
    for (int w = 1; w < 64; ++w) {
        int ns = 64 - w;
        int g  = (w == 1) ? 1 : (1 << (32 - __clz(w - 1)));   // pow2ceil(w)
        int spw  = 64 / g;            // spans per wave
        int sub  = lane & (g - 1);    // term index within span
        int grp  = lane / g;          // span group within wave
        int slot = wv * spw + grp;    // global span slot
        int slots = 16 * spw;
        // ---------------- Phase A: incomplete spans
        {
            int i0 = slot, i1 = slot + slots;
            bool v0 = (i0 < ns), v1 = (i1 < ns);
            float va0 = -INFINITY, va1 = -INFINITY;
            if (v0 && sub < w) va0 = bufR[i0][i0 + sub] + bufL[i0 + sub + 1][i0 + w];
            if (v1 && sub < w) va1 = bufR[i1][i1 + sub] + bufL[i1 + sub + 1][i1 + w];
            float m0 = va0, m1 = va1;
            for (int off = g >> 1; off; off >>= 1) {
                m0 = fmaxf(m0, __shfl_xor(m0, off));
                m1 = fmaxf(m1, __shfl_xor(m1, off));
            }
            float e0 = expf(va0 - m0), e1 = expf(va1 - m1);
            for (int off = g >> 1; off; off >>= 1) {
                e0 += __shfl_xor(e0, off);
                e1 += __shfl_xor(e1, off);
            }
            if (v0 && sub == 0) {
                float inc = m0 + logf(e0);
                int j = i0 + w;
                bufR[j][i0] = inc + su[i0] + sv[j] + bsv;   // I_r[i0][j]
                bufL[j][i0] = inc + su[j] + sv[i0] + bsv;   // I_l[i0][j]
            }
            if (v1 && sub == 0) {
                float inc = m1 + logf(e1);
                int j = i1 + w;
                bufR[j][i1] = inc + su[i1] + sv[j] + bsv;
                bufL[j][i1] = inc + su[j] + sv[i1] + bsv;
            }
        }
        __syncthreads();
        // ---------------- Phase B: complete spans
        {
            int i0 = slot, i1 = slot + slots;
            bool v0 = (i0 < ns), v1 = (i1 < ns);
            float vr0 = -INFINITY, vl0 = -INFINITY, vr1 = -INFINITY, vl1 = -INFINITY;
            if (v0 && sub < w) {
                int j = i0 + w;
                vr0 = bufR[i0 + 1 + sub][i0] + bufR[i0 + 1 + sub][j];  // I_r[i0][k]+C_r[k][j]
                vl0 = bufL[i0][i0 + sub]     + bufL[j][i0 + sub];      // C_l[i0][k]+I_l[k][j]
            }
            if (v1 && sub < w) {
                int j = i1 + w;
                vr1 = bufR[i1 + 1 + sub][i1] + bufR[i1 + 1 + sub][j];
                vl1 = bufL[i1][i1 + sub]     + bufL[j][i1 + sub];
            }
            float mr0 = vr0, ml0 = vl0, mr1 = vr1, ml1 = vl1;
            for (int off = g >> 1; off; off >>= 1) {
                mr0 = fmaxf(mr0, __shfl_xor(mr0, off));
                ml0 = fmaxf(ml0, __shfl_xor(ml0, off));
                mr1 = fmaxf(mr1, __shfl_xor(mr1, off));
                ml1 = fmaxf(ml1, __shfl_xor(ml1, off));
            }
            float er0 = expf(vr0 - mr0), el0 = expf(vl0 - ml0);
            float er1 = expf(vr1 - mr1), el1 = expf(vl1 - ml1);
            for (int off = g >> 1; off; off >>= 1) {
                er0 += __shfl_xor(er0, off);
                el0 += __shfl_xor(el0, off);
                er1 += __shfl_xor(er1, off);
                el1 += __shfl_xor(el1, off);
            }
            if (v0 && sub == 0) {
                int j = i0 + w;
                bufR[i0][j] = mr0 + logf(er0);   // C_r[i0][j]
                bufL[i0][j] = ml0 + logf(el0);   // C_l[i0][j]
            }
            if (v1 && sub == 0) {
                int j = i1 + w;
                bufR[i1][j] = mr1 + logf(er1);
                bufL[i1][j] = ml1 + logf(el1);
            }
        }
        __syncthreads();
    }
    if (tid == 0) logZ[b] = bufR[0][63];
}

// ---------------------------------------------------------------- final loss
__global__ __launch_bounds__(512) void finalize(const float* __restrict__ u,
                                                const float* __restrict__ v,
                                                const float* __restrict__ bs,
                                                const float* __restrict__ S,
                                                const float* __restrict__ lseS,
                                                const float* __restrict__ prior,
                                                const int* __restrict__ heads,
                                                const float* __restrict__ logZ,
                                                float* __restrict__ out) {
    int b = threadIdx.x >> 6;      // 8 waves, one per batch
    int m = threadIdx.x & 63;
    __shared__ float red[8];
    float gv = -INFINITY;
    if (m >= 1) {
        int hd = heads[b*64 + m];
        float crf = u[b*64 + hd] + v[b*64 + m] + bs[0];
        float rec = S[(size_t)(b*64 + hd)*64 + m] - lseS[b*64 + hd];
        gv = crf + rec + prior[(size_t)(b*64 + hd)*64 + m] * (1.0f/64.0f);
    }
    float mm = gv;
    for (int off = 32; off; off >>= 1) mm = fmaxf(mm, __shfl_xor(mm, off));
    float se = (m >= 1) ? expf(gv - mm) : 0.0f;
    for (int off = 32; off; off >>= 1) se += __shfl_xor(se, off);
    if (m == 0) red[b] = (mm + logf(se)) - logZ[b];
    __syncthreads();
    if (threadIdx.x == 0) {
        float a = 0.0f;
        for (int q = 0; q < 8; ++q) a += red[q];
        out[0] = -(a / 8.0f);
    }
}

// ---------------------------------------------------------------- launch
extern "C" void kernel_launch(void* const* d_in, const int* in_sizes, int n_in,
                              void* d_out, int out_size, void* d_ws, size_t ws_size,
                              hipStream_t stream) {
    const int*   sents = (const int*)  d_in[0];
    const float* mask  = (const float*)d_in[1];
    const float* prior = (const float*)d_in[2];
    const int*   heads = (const int*)  d_in[3];
    const float* emb   = (const float*)d_in[4];
    const float* Wih_f = (const float*)d_in[5];
    const float* Whh_f = (const float*)d_in[6];
    const float* bih_f = (const float*)d_in[7];
    const float* bhh_f = (const float*)d_in[8];
    const float* Wih_b = (const float*)d_in[9];
    const float* Whh_b = (const float*)d_in[10];
    const float* bih_b = (const float*)d_in[11];
    const float* bhh_b = (const float*)d_in[12];
    const float* W1    = (const float*)d_in[13];
    const float* b1    = (const float*)d_in[14];
    const float* W2    = (const float*)d_in[15];
    const float* b2    = (const float*)d_in[16];
    const float* Ws    = (const float*)d_in[17];
    const float* bs    = (const float*)d_in[18];
    float* out = (float*)d_out;

    char* w = (char*)d_ws;
    float* embeds = (float*)(w + 0);                    // 512 KB
    float* gxf    = (float*)(w + 524288);               // 2 MB
    float* gxb    = (float*)(w + 2621440);              // 2 MB
    __hip_bfloat162* wTf = (__hip_bfloat162*)(w + 4718592);  // 512 KB
    __hip_bfloat162* wTb = (__hip_bfloat162*)(w + 5242880);  // 512 KB
    float* biasf  = (float*)(w + 5767168);              // 4 KB
    float* biasb  = (float*)(w + 5771264);              // 4 KB
    float* hall   = (float*)(w + 5775360);              // 1 MB
    float* uArr   = (float*)(w + 6823936);              // 2 KB
    float* vArr   = (float*)(w + 6825984);              // 2 KB
    float* p1     = (float*)(w + 6828032);              // 256 KB
    float* p2     = (float*)(w + 7090176);              // 256 KB
    float* S      = (float*)(w + 7352320);              // 128 KB
    float* lseS   = (float*)(w + 7483392);              // 2 KB
    float* logZ   = (float*)(w + 7485440);              // 32 B

    prep_weights<<<1024, 256, 0, stream>>>(Whh_f, Whh_b, bih_f, bhh_f, bih_b, bhh_b,
                                           wTf, wTb, biasf, biasb);
    embed_mean<<<512, 256, 0, stream>>>(sents, mask, emb, embeds);
    gemm32<<<dim3(16,32,1), 256, 0, stream>>>(embeds, Wih_f, biasf, gxf, 1024, 256, 0,0,0);
    gemm32<<<dim3(16,32,1), 256, 0, stream>>>(embeds, Wih_b, biasb, gxb, 1024, 256, 0,0,0);
    lstm_rec<<<64, 256, 0, stream>>>(gxf, gxb, wTf, wTb, hall);
    uv_kernel<<<512, 256, 0, stream>>>(hall, Ws, uArr, vArr);
    gemm32<<<dim3(16,4,1), 256, 0, stream>>>(hall, W1, b1, p1, 128, 512, 0,0,0);
    gemm32<<<dim3(16,4,1), 256, 0, stream>>>(hall, W2, b2, p2, 128, 512, 0,0,0);
    gemm32<<<dim3(2,2,8), 256, 0, stream>>>(p1, p2, nullptr, S, 64, 128, 8192, 8192, 4096);
    row_lse<<<8, 256, 0, stream>>>(S, lseS);
    eisner<<<8, 1024, 0, stream>>>(uArr, vArr, bs, logZ);
    finalize<<<1, 512, 0, stream>>>(uArr, vArr, bs, S, lseS, prior, heads, logZ, out);
    (void)in_sizes; (void)n_in; (void)out_size; (void)ws_size;
}

// Round 3
// 528.382 us; speedup vs baseline: 1.1476x; 1.0608x over previous
//
#include <hip/hip_runtime.h>
#include <hip/hip_bf16.h>
#include <math.h>

#define NEGV -1000000000.0f

__device__ __forceinline__ float sigf(float x){ return 1.0f/(1.0f+expf(-x)); }

// ---------------------------------------------------------------- prep + embed + out-zero
// blocks 0..1023: pack Whh -> bf16 [k2][gate] + bias add
// blocks 1024..1535: embed mean (bl = blockIdx-1024)
__global__ __launch_bounds__(256) void prep_all(const float* __restrict__ Whh_f, const float* __restrict__ Whh_b,
                             const float* __restrict__ bih_f, const float* __restrict__ bhh_f,
                             const float* __restrict__ bih_b, const float* __restrict__ bhh_b,
                             __hip_bfloat162* __restrict__ wTf, __hip_bfloat162* __restrict__ wTb,
                             float* __restrict__ biasf, float* __restrict__ biasb,
                             const int* __restrict__ sents, const float* __restrict__ mask,
                             const float* __restrict__ emb, float* __restrict__ embeds,
                             float* __restrict__ out) {
    if (blockIdx.x < 1024) {
        int idx = blockIdx.x * 256 + threadIdx.x;      // 0 .. 262143
        int dir = idx >> 17;
        int r   = idx & 131071;
        int k2  = r >> 10;
        int g   = r & 1023;
        const float* W = dir ? Whh_b : Whh_f;
        __hip_bfloat162 t;
        t.x = __float2bfloat16(W[g*256 + 2*k2]);
        t.y = __float2bfloat16(W[g*256 + 2*k2 + 1]);
        (dir ? wTb : wTf)[r] = t;
        if (idx < 1024)       biasf[idx]      = bih_f[idx]      + bhh_f[idx];
        else if (idx < 2048)  biasb[idx-1024] = bih_b[idx-1024] + bhh_b[idx-1024];
        if (idx == 0) out[0] = 0.0f;
    } else {
        int bl = blockIdx.x - 1024;   // 0..511
        int d  = threadIdx.x;         // 0..255
        const int*   srow = sents + bl*32;
        const float* mrow = mask  + bl*32;
        float acc = 0.0f, el = 0.0f;
        for (int w = 0; w < 32; ++w) {
            float m = mrow[w];
            el  += m;
            acc += emb[(size_t)srow[w]*256 + d] * m;
        }
        float den = el + (el == 0.0f ? 1.0f : 0.0f);
        embeds[bl*256 + d] = acc / den;
    }
}

// ---------------------------------------------------------------- shared GEMM body
// C[m][n] = sum_k A[m][k]*B[n][k] + bias[n];  32x32 tile at (bx,by), 256 thr.
__device__ __forceinline__ void gemm_body(const float* __restrict__ A,
                                          const float* __restrict__ Bm,
                                          const float* __restrict__ bias,
                                          float* __restrict__ C,
                                          int N, int K, int bx, int by) {
    __shared__ float As[32][33];   // [k][m]
    __shared__ float Bs[32][33];   // [k][n]
    int tid = threadIdx.x;
    int tx = tid & 15, ty = tid >> 4;
    int row0 = bx * 32, col0 = by * 32;
    float a00=0.f, a01=0.f, a10=0.f, a11=0.f;
    int e = tid * 4;
    int lr = e >> 5, lc = e & 31;
    for (int k0 = 0; k0 < K; k0 += 32) {
        const float* ap = A  + (size_t)(row0+lr)*K + k0 + lc;
        const float* bp = Bm + (size_t)(col0+lr)*K + k0 + lc;
        As[lc  ][lr] = ap[0]; As[lc+1][lr] = ap[1]; As[lc+2][lr] = ap[2]; As[lc+3][lr] = ap[3];
        Bs[lc  ][lr] = bp[0]; Bs[lc+1][lr] = bp[1]; Bs[lc+2][lr] = bp[2]; Bs[lc+3][lr] = bp[3];
        __syncthreads();
        #pragma unroll
        for (int kc = 0; kc < 32; ++kc) {
            float x0 = As[kc][ty*2], x1 = As[kc][ty*2+1];
            float y0 = Bs[kc][tx*2], y1 = Bs[kc][tx*2+1];
            a00 = fmaf(x0,y0,a00); a01 = fmaf(x0,y1,a01);
            a10 = fmaf(x1,y0,a10); a11 = fmaf(x1,y1,a11);
        }
        __syncthreads();
    }
    int rr = row0 + ty*2, cc = col0 + tx*2;
    float b0 = bias ? bias[cc]   : 0.0f;
    float b1 = bias ? bias[cc+1] : 0.0f;
    C[(size_t)rr*N + cc]       = a00 + b0;
    C[(size_t)rr*N + cc + 1]   = a01 + b1;
    C[(size_t)(rr+1)*N + cc]   = a10 + b0;
    C[(size_t)(rr+1)*N + cc+1] = a11 + b1;
}

// gx = embeds @ Wih^T + bias, both directions via z
__global__ __launch_bounds__(256) void gemm_ih(const float* __restrict__ embeds,
                                               const float* __restrict__ Wf, const float* __restrict__ Wb,
                                               const float* __restrict__ biasf, const float* __restrict__ biasb,
                                               float* __restrict__ gxf, float* __restrict__ gxb) {
    int dir = blockIdx.z;
    gemm_body(embeds, dir ? Wb : Wf, dir ? biasb : biasf, dir ? gxb : gxf,
              1024, 256, blockIdx.x, blockIdx.y);
}

// generic (used for batched S gemm)
__global__ __launch_bounds__(256) void gemm32(const float* __restrict__ A,
                                              const float* __restrict__ Bm,
                                              const float* __restrict__ bias,
                                              float* __restrict__ C,
                                              int N, int K, int sA, int sB, int sC) {
    gemm_body(A + (size_t)blockIdx.z * sA, Bm + (size_t)blockIdx.z * sB, bias,
              C + (size_t)blockIdx.z * sC, N, K, blockIdx.x, blockIdx.y);
}

// ---------------------------------------------------------------- LSTM recurrence
__global__ __launch_bounds__(256) void lstm_rec(const float* __restrict__ gxf,
                                                const float* __restrict__ gxb,
                                                const __hip_bfloat162* __restrict__ wTf,
                                                const __hip_bfloat162* __restrict__ wTb,
                                                float* __restrict__ hall) {
    int blk  = blockIdx.x;        // 0..63
    int dir  = blk >> 5;
    int pair = blk & 31;
    int p0 = pair*2, p1 = p0 + 1;
    int j  = threadIdx.x;         // cell 0..255
    const float* gx = dir ? gxb : gxf;
    const __hip_bfloat162* wT = dir ? wTb : wTf;
    __shared__ float h0s[256], h1s[256];
    h0s[j] = 0.0f; h1s[j] = 0.0f;
    float c0 = 0.0f, c1 = 0.0f;
    __syncthreads();
    for (int s = 0; s < 8; ++s) {
        int t = dir ? (7 - s) : s;
        const float* g0 = gx + (size_t)(t*64 + p0)*1024;
        const float* g1 = gx + (size_t)(t*64 + p1)*1024;
        float ai0 = g0[j], af0 = g0[256+j], ag0 = g0[512+j], ao0 = g0[768+j];
        float ai1 = g1[j], af1 = g1[256+j], ag1 = g1[512+j], ao1 = g1[768+j];
        for (int k2 = 0; k2 < 128; ++k2) {
            const __hip_bfloat162* wrow = wT + k2*1024 + j;
            float2 wi = __bfloat1622float2(wrow[0]);
            float2 wf = __bfloat1622float2(wrow[256]);
            float2 wg = __bfloat1622float2(wrow[512]);
            float2 wo = __bfloat1622float2(wrow[768]);
            float ha = h0s[2*k2], hb = h0s[2*k2+1];
            float hc = h1s[2*k2], hd = h1s[2*k2+1];
            ai0 = fmaf(wi.x,ha, fmaf(wi.y,hb, ai0));
            af0 = fmaf(wf.x,ha, fmaf(wf.y,hb, af0));
            ag0 = fmaf(wg.x,ha, fmaf(wg.y,hb, ag0));
            ao0 = fmaf(wo.x,ha, fmaf(wo.y,hb, ao0));
            ai1 = fmaf(wi.x,hc, fmaf(wi.y,hd, ai1));
            af1 = fmaf(wf.x,hc, fmaf(wf.y,hd, af1));
            ag1 = fmaf(wg.x,hc, fmaf(wg.y,hd, ag1));
            ao1 = fmaf(wo.x,hc, fmaf(wo.y,hd, ao1));
        }
        __syncthreads();
        c0 = sigf(af0)*c0 + sigf(ai0)*tanhf(ag0);
        float h0 = sigf(ao0)*tanhf(c0);
        c1 = sigf(af1)*c1 + sigf(ai1)*tanhf(ag1);
        float h1 = sigf(ao1)*tanhf(c1);
        h0s[j] = h0; h1s[j] = h1;
        hall[(size_t)(t*64 + p0)*512 + dir*256 + j] = h0;
        hall[(size_t)(t*64 + p1)*512 + dir*256 + j] = h1;
        __syncthreads();
    }
}

// ---------------------------------------------------------------- uv + p1 + p2 fused
// blocks 0..511: uv;  512..575: p1 gemm;  576..639: p2 gemm
__global__ __launch_bounds__(256) void post_lstm(const float* __restrict__ hall,
                                                 const float* __restrict__ Ws,
                                                 float* __restrict__ u, float* __restrict__ v,
                                                 const float* __restrict__ W1, const float* __restrict__ b1,
                                                 const float* __restrict__ W2, const float* __restrict__ b2,
                                                 float* __restrict__ p1, float* __restrict__ p2) {
    if (blockIdx.x < 512) {
        int bi = blockIdx.x;
        int i  = bi & 63;
        int tid = threadIdx.x;
        float pu = 0.0f, pv = 0.0f;
        for (int q = tid; q < 1536; q += 256) {
            int seg = q >> 9, kk = q & 511;
            float tv = 0.0f;
            if (seg == 0)       tv = hall[(size_t)bi*512 + kk];
            else if (seg == 1)  { if (i > 0)  tv = hall[(size_t)(bi-1)*512 + kk]; }
            else                { if (i < 63) tv = hall[(size_t)(bi+1)*512 + kk]; }
            pu = fmaf(tv, Ws[q],        pu);
            pv = fmaf(tv, Ws[1536 + q], pv);
        }
        for (int off = 32; off; off >>= 1) { pu += __shfl_xor(pu, off); pv += __shfl_xor(pv, off); }
        __shared__ float ru[4], rv[4];
        int wv = tid >> 6, lane = tid & 63;
        if (lane == 0) { ru[wv] = pu; rv[wv] = pv; }
        __syncthreads();
        if (tid == 0) { u[bi] = ru[0]+ru[1]+ru[2]+ru[3]; v[bi] = rv[0]+rv[1]+rv[2]+rv[3]; }
    } else {
        int blk = blockIdx.x - 512;
        int sel = blk >> 6; blk &= 63;
        gemm_body(hall, sel ? W2 : W1, sel ? b2 : b1, sel ? p2 : p1,
                  128, 512, blk & 15, blk >> 4);
    }
}

// ---------------------------------------------------------------- Eisner + row_lse + finalize
// One block per batch, 1024 threads. ONE barrier per width:
//   C_r[i,j] = logaddexp( lse_{k=i+1..j-1}(I_r[i,k]+C_r[k,j]),  I_r[i,j] )
//   C_l[i,j] = logaddexp( lse_{k=i+1..j-1}(C_l[i,k]+I_l[k,j]),  I_l[i,j] )
// where the lse parts use only width<w entries -> computable in the same
// phase as inc (also width<w), so I and C of width w commit together.
//   bufR upper+diag = C_r[i][j]; bufR lower [j][i] = I_r[i][j]; same for L.
__global__ __launch_bounds__(1024) void eisner_final(const float* __restrict__ u,
                                                     const float* __restrict__ v,
                                                     const float* __restrict__ bs,
                                                     const float* __restrict__ S,
                                                     const float* __restrict__ prior,
                                                     const int* __restrict__ heads,
                                                     float* __restrict__ out) {
    int b = blockIdx.x;
    __shared__ float bufR[64][65];
    __shared__ float bufL[64][65];
    __shared__ float Sm[64][65];
    __shared__ float su[64], sv[64], lseSb[64];
    int tid = threadIdx.x;
    // stage S tile, u/v, init DP tables
    for (int e = tid; e < 4096; e += 1024) {
        int r = e >> 6, c = e & 63;
        Sm[r][c] = S[(size_t)(b*64 + r)*64 + c];
    }
    if (tid < 64) { su[tid] = u[b*64 + tid]; sv[tid] = v[b*64 + tid]; }
    float bsv = bs[0];
    for (int e = tid; e < 64*65; e += 1024) {
        int i = e / 65, jj = e % 65;
        float val = (i == jj) ? 0.0f : -INFINITY;
        bufR[i][jj] = val; bufL[i][jj] = val;
    }
    __syncthreads();
    int wv = tid >> 6, lane = tid & 63;
    // row logsumexp of Sm (writes lseSb; read only at finalize, after many syncs)
    for (int r = wv; r < 64; r += 16) {
        float x = Sm[r][lane];
        float m = x;
        for (int off = 32; off; off >>= 1) m = fmaxf(m, __shfl_xor(m, off));
        float se = expf(x - m);
        for (int off = 32; off; off >>= 1) se += __shfl_xor(se, off);
        if (lane == 0) lseSb[r] = m + logf(se);
    }
    // DP: one barrier per width
    for (int w = 1; w < 64; ++w) {
        int ns = 64 - w;
        int g  = (w == 1) ? 1 : (1 << (32 - __clz(w - 1)));   // pow2ceil(w)
        int spw  = 64 / g;
        int sub  = lane & (g - 1);
        int grp  = lane / g;
        int slot = wv * spw + grp;
        int slots = spw << 4;
        int i0 = slot, i1 = slot + slots;
        bool ok0 = (i0 < ns), ok1 = (i1 < ns);
        int j0 = i0 + w, j1 = i1 + w;
        float a0 = -INFINITY, a1 = -INFINITY;   // inc terms
        float r0 = -INFINITY, r1 = -INFINITY;   // partR terms
        float l0 = -INFINITY, l1 = -INFINITY;   // partL terms
        if (ok0) {
            if (sub < w) a0 = bufR[i0][i0 + sub] + bufL[i0 + sub + 1][j0];
            if (sub < w - 1) {
                int k = i0 + 1 + sub;
                r0 = bufR[k][i0] + bufR[k][j0];   // I_r[i0][k] + C_r[k][j0]
                l0 = bufL[i0][k] + bufL[j0][k];   // C_l[i0][k] + I_l[k][j0]
            }
        }
        if (ok1) {
            if (sub < w) a1 = bufR[i1][i1 + sub] + bufL[i1 + sub + 1][j1];
            if (sub < w - 1) {
                int k = i1 + 1 + sub;
                r1 = bufR[k][i1] + bufR[k][j1];
                l1 = bufL[i1][k] + bufL[j1][k];
            }
        }
        float ma0=a0, ma1=a1, mr0=r0, mr1=r1, ml0=l0, ml1=l1;
        for (int off = g >> 1; off; off >>= 1) {
            ma0 = fmaxf(ma0, __shfl_xor(ma0, off));
            ma1 = fmaxf(ma1, __shfl_xor(ma1, off));
            mr0 = fmaxf(mr0, __shfl_xor(mr0, off));
            mr1 = fmaxf(mr1, __shfl_xor(mr1, off));
            ml0 = fmaxf(ml0, __shfl_xor(ml0, off));
            ml1 = fmaxf(ml1, __shfl_xor(ml1, off));
        }
        float ea0 = expf(a0 - ma0), ea1 = expf(a1 - ma1);
        float er0 = expf(r0 - mr0), er1 = expf(r1 - mr1);
        float el0 = expf(l0 - ml0), el1 = expf(l1 - ml1);
        for (int off = g >> 1; off; off >>= 1) {
            ea0 += __shfl_xor(ea0, off);
            ea1 += __shfl_xor(ea1, off);
            er0 += __shfl_xor(er0, off);
            er1 += __shfl_xor(er1, off);
            el0 += __shfl_xor(el0, off);
            el1 += __shfl_xor(el1, off);
        }
        if (ok0 && sub == 0) {
            float inc = ma0 + logf(ea0);
            float Ir = inc + su[i0] + sv[j0] + bsv;
            float Il = inc + su[j0] + sv[i0] + bsv;
            float pr = (mr0 == -INFINITY) ? -INFINITY : mr0 + logf(er0);
            float pl = (ml0 == -INFINITY) ? -INFINITY : ml0 + logf(el0);
            float Mr = fmaxf(pr, Ir);
            float Cr = Mr + logf(expf(pr - Mr) + expf(Ir - Mr));
            float Ml = fmaxf(pl, Il);
            float Cl = Ml + logf(expf(pl - Ml) + expf(Il - Ml));
            bufR[j0][i0] = Ir; bufL[j0][i0] = Il;
            bufR[i0][j0] = Cr; bufL[i0][j0] = Cl;
        }
        if (ok1 && sub == 0) {
            float inc = ma1 + logf(ea1);
            float Ir = inc + su[i1] + sv[j1] + bsv;
            float Il = inc + su[j1] + sv[i1] + bsv;
            float pr = (mr1 == -INFINITY) ? -INFINITY : mr1 + logf(er1);
            float pl = (ml1 == -INFINITY) ? -INFINITY : ml1 + logf(el1);
            float Mr = fmaxf(pr, Ir);
            float Cr = Mr + logf(expf(pr - Mr) + expf(Ir - Mr));
            float Ml = fmaxf(pl, Il);
            float Cl = Ml + logf(expf(pl - Ml) + expf(Il - Ml));
            bufR[j1][i1] = Ir; bufL[j1][i1] = Il;
            bufR[i1][j1] = Cr; bufL[i1][j1] = Cl;
        }
        __syncthreads();
    }
    // finalize for this batch (wave 0)
    if (tid < 64) {
        int m = tid;
        float logZv = bufR[0][63];
        float gv = -INFINITY;
        if (m >= 1) {
            int hd = heads[b*64 + m];
            float crf = su[hd] + sv[m] + bsv;
            float rec = Sm[hd][m] - lseSb[hd];
            gv = crf + rec + prior[(size_t)(b*64 + hd)*64 + m] * (1.0f/64.0f);
        }
        float mm = gv;
        for (int off = 32; off; off >>= 1) mm = fmaxf(mm, __shfl_xor(mm, off));
        float se = (m >= 1) ? expf(gv - mm) : 0.0f;
        for (int off = 32; off; off >>= 1) se += __shfl_xor(se, off);
        if (m == 0) {
            float red = (mm + logf(se)) - logZv;
            atomicAdd(out, -red * 0.125f);
        }
    }
}

// ---------------------------------------------------------------- launch
extern "C" void kernel_launch(void* const* d_in, const int* in_sizes, int n_in,
                              void* d_out, int out_size, void* d_ws, size_t ws_size,
                              hipStream_t stream) {
    const int*   sents = (const int*)  d_in[0];
    const float* mask  = (const float*)d_in[1];
    const float* prior = (const float*)d_in[2];
    const int*   heads = (const int*)  d_in[3];
    const float* emb   = (const float*)d_in[4];
    const float* Wih_f = (const float*)d_in[5];
    const float* Whh_f = (const float*)d_in[6];
    const float* bih_f = (const float*)d_in[7];
    const float* bhh_f = (const float*)d_in[8];
    const float* Wih_b = (const float*)d_in[9];
    const float* Whh_b = (const float*)d_in[10];
    const float* bih_b = (const float*)d_in[11];
    const float* bhh_b = (const float*)d_in[12];
    const float* W1    = (const float*)d_in[13];
    const float* b1    = (const float*)d_in[14];
    const float* W2    = (const float*)d_in[15];
    const float* b2    = (const float*)d_in[16];
    const float* Ws    = (const float*)d_in[17];
    const float* bs    = (const float*)d_in[18];
    float* out = (float*)d_out;

    char* w = (char*)d_ws;
    float* embeds = (float*)(w + 0);                    // 512 KB
    float* gxf    = (float*)(w + 524288);               // 2 MB
    float* gxb    = (float*)(w + 2621440);              // 2 MB
    __hip_bfloat162* wTf = (__hip_bfloat162*)(w + 4718592);  // 512 KB
    __hip_bfloat162* wTb = (__hip_bfloat162*)(w + 5242880);  // 512 KB
    float* biasf  = (float*)(w + 5767168);              // 4 KB
    float* biasb  = (float*)(w + 5771264);              // 4 KB
    float* hall   = (float*)(w + 5775360);              // 1 MB
    float* uArr   = (float*)(w + 6823936);              // 2 KB
    float* vArr   = (float*)(w + 6825984);              // 2 KB
    float* p1     = (float*)(w + 6828032);              // 256 KB
    float* p2     = (float*)(w + 7090176);              // 256 KB
    float* S      = (float*)(w + 7352320);              // 128 KB

    prep_all<<<1536, 256, 0, stream>>>(Whh_f, Whh_b, bih_f, bhh_f, bih_b, bhh_b,
                                       wTf, wTb, biasf, biasb,
                                       sents, mask, emb, embeds, out);
    gemm_ih<<<dim3(16,32,2), 256, 0, stream>>>(embeds, Wih_f, Wih_b, biasf, biasb, gxf, gxb);
    lstm_rec<<<64, 256, 0, stream>>>(gxf, gxb, wTf, wTb, hall);
    post_lstm<<<640, 256, 0, stream>>>(hall, Ws, uArr, vArr, W1, b1, W2, b2, p1, p2);
    gemm32<<<dim3(2,2,8), 256, 0, stream>>>(p1, p2, nullptr, S, 64, 128, 8192, 8192, 4096);
    eisner_final<<<8, 1024, 0, stream>>>(uArr, vArr, bs, S, prior, heads, out);
    (void)in_sizes; (void)n_in; (void)out_size; (void)ws_size;
}

// Round 4
// 444.394 us; speedup vs baseline: 1.3644x; 1.1890x over previous
//
#include <hip/hip_runtime.h>
#include <hip/hip_bf16.h>
#include <math.h>

#define L2E 1.44269504f
#define LN2 0.69314718f

__device__ __forceinline__ float sigf(float x){ return 1.0f/(1.0f+expf(-x)); }

// quad (4-lane) reductions via DPP quad_perm — VALU pipe, no LDS latency
__device__ __forceinline__ float quad_max(float x) {
    x = fmaxf(x, __int_as_float(__builtin_amdgcn_mov_dpp(__float_as_int(x), 0xB1, 0xF, 0xF, true)));
    x = fmaxf(x, __int_as_float(__builtin_amdgcn_mov_dpp(__float_as_int(x), 0x4E, 0xF, 0xF, true)));
    return x;
}
__device__ __forceinline__ float quad_sum(float x) {
    x += __int_as_float(__builtin_amdgcn_mov_dpp(__float_as_int(x), 0xB1, 0xF, 0xF, true));
    x += __int_as_float(__builtin_amdgcn_mov_dpp(__float_as_int(x), 0x4E, 0xF, 0xF, true));
    return x;
}

// ---------------------------------------------------------------- prep + embed + out-zero
__global__ __launch_bounds__(256) void prep_all(const float* __restrict__ Whh_f, const float* __restrict__ Whh_b,
                             const float* __restrict__ bih_f, const float* __restrict__ bhh_f,
                             const float* __restrict__ bih_b, const float* __restrict__ bhh_b,
                             __hip_bfloat162* __restrict__ wTf, __hip_bfloat162* __restrict__ wTb,
                             float* __restrict__ biasf, float* __restrict__ biasb,
                             const int* __restrict__ sents, const float* __restrict__ mask,
                             const float* __restrict__ emb, float* __restrict__ embeds,
                             float* __restrict__ out) {
    if (blockIdx.x < 1024) {
        int idx = blockIdx.x * 256 + threadIdx.x;      // 0 .. 262143
        int dir = idx >> 17;
        int r   = idx & 131071;
        int k2  = r >> 10;
        int g   = r & 1023;
        const float* W = dir ? Whh_b : Whh_f;
        __hip_bfloat162 t;
        t.x = __float2bfloat16(W[g*256 + 2*k2]);
        t.y = __float2bfloat16(W[g*256 + 2*k2 + 1]);
        (dir ? wTb : wTf)[r] = t;
        if (idx < 1024)       biasf[idx]      = bih_f[idx]      + bhh_f[idx];
        else if (idx < 2048)  biasb[idx-1024] = bih_b[idx-1024] + bhh_b[idx-1024];
        if (idx == 0) out[0] = 0.0f;
    } else {
        int bl = blockIdx.x - 1024;   // 0..511
        int d  = threadIdx.x;         // 0..255
        const int*   srow = sents + bl*32;
        const float* mrow = mask  + bl*32;
        float acc = 0.0f, el = 0.0f;
        for (int w = 0; w < 32; ++w) {
            float m = mrow[w];
            el  += m;
            acc += emb[(size_t)srow[w]*256 + d] * m;
        }
        float den = el + (el == 0.0f ? 1.0f : 0.0f);
        embeds[bl*256 + d] = acc / den;
    }
}

// ---------------------------------------------------------------- shared GEMM body
__device__ __forceinline__ void gemm_body(const float* __restrict__ A,
                                          const float* __restrict__ Bm,
                                          const float* __restrict__ bias,
                                          float* __restrict__ C,
                                          int N, int K, int bx, int by) {
    __shared__ float As[32][33];   // [k][m]
    __shared__ float Bs[32][33];   // [k][n]
    int tid = threadIdx.x;
    int tx = tid & 15, ty = tid >> 4;
    int row0 = bx * 32, col0 = by * 32;
    float a00=0.f, a01=0.f, a10=0.f, a11=0.f;
    int e = tid * 4;
    int lr = e >> 5, lc = e & 31;
    for (int k0 = 0; k0 < K; k0 += 32) {
        const float* ap = A  + (size_t)(row0+lr)*K + k0 + lc;
        const float* bp = Bm + (size_t)(col0+lr)*K + k0 + lc;
        As[lc  ][lr] = ap[0]; As[lc+1][lr] = ap[1]; As[lc+2][lr] = ap[2]; As[lc+3][lr] = ap[3];
        Bs[lc  ][lr] = bp[0]; Bs[lc+1][lr] = bp[1]; Bs[lc+2][lr] = bp[2]; Bs[lc+3][lr] = bp[3];
        __syncthreads();
        #pragma unroll
        for (int kc = 0; kc < 32; ++kc) {
            float x0 = As[kc][ty*2], x1 = As[kc][ty*2+1];
            float y0 = Bs[kc][tx*2], y1 = Bs[kc][tx*2+1];
            a00 = fmaf(x0,y0,a00); a01 = fmaf(x0,y1,a01);
            a10 = fmaf(x1,y0,a10); a11 = fmaf(x1,y1,a11);
        }
        __syncthreads();
    }
    int rr = row0 + ty*2, cc = col0 + tx*2;
    float b0 = bias ? bias[cc]   : 0.0f;
    float b1 = bias ? bias[cc+1] : 0.0f;
    C[(size_t)rr*N + cc]       = a00 + b0;
    C[(size_t)rr*N + cc + 1]   = a01 + b1;
    C[(size_t)(rr+1)*N + cc]   = a10 + b0;
    C[(size_t)(rr+1)*N + cc+1] = a11 + b1;
}

__global__ __launch_bounds__(256) void gemm_ih(const float* __restrict__ embeds,
                                               const float* __restrict__ Wf, const float* __restrict__ Wb,
                                               const float* __restrict__ biasf, const float* __restrict__ biasb,
                                               float* __restrict__ gxf, float* __restrict__ gxb) {
    int dir = blockIdx.z;
    gemm_body(embeds, dir ? Wb : Wf, dir ? biasb : biasf, dir ? gxb : gxf,
              1024, 256, blockIdx.x, blockIdx.y);
}

__global__ __launch_bounds__(256) void gemm32(const float* __restrict__ A,
                                              const float* __restrict__ Bm,
                                              const float* __restrict__ bias,
                                              float* __restrict__ C,
                                              int N, int K, int sA, int sB, int sC) {
    gemm_body(A + (size_t)blockIdx.z * sA, Bm + (size_t)blockIdx.z * sB, bias,
              C + (size_t)blockIdx.z * sC, N, K, blockIdx.x, blockIdx.y);
}

// ---------------------------------------------------------------- LSTM recurrence
__global__ __launch_bounds__(256) void lstm_rec(const float* __restrict__ gxf,
                                                const float* __restrict__ gxb,
                                                const __hip_bfloat162* __restrict__ wTf,
                                                const __hip_bfloat162* __restrict__ wTb,
                                                float* __restrict__ hall) {
    int blk  = blockIdx.x;        // 0..63
    int dir  = blk >> 5;
    int pair = blk & 31;
    int p0 = pair*2, p1 = p0 + 1;
    int j  = threadIdx.x;         // cell 0..255
    const float* gx = dir ? gxb : gxf;
    const __hip_bfloat162* wT = dir ? wTb : wTf;
    __shared__ float h0s[256], h1s[256];
    h0s[j] = 0.0f; h1s[j] = 0.0f;
    float c0 = 0.0f, c1 = 0.0f;
    __syncthreads();
    for (int s = 0; s < 8; ++s) {
        int t = dir ? (7 - s) : s;
        const float* g0 = gx + (size_t)(t*64 + p0)*1024;
        const float* g1 = gx + (size_t)(t*64 + p1)*1024;
        float ai0 = g0[j], af0 = g0[256+j], ag0 = g0[512+j], ao0 = g0[768+j];
        float ai1 = g1[j], af1 = g1[256+j], ag1 = g1[512+j], ao1 = g1[768+j];
        for (int k2 = 0; k2 < 128; ++k2) {
            const __hip_bfloat162* wrow = wT + k2*1024 + j;
            float2 wi = __bfloat1622float2(wrow[0]);
            float2 wf = __bfloat1622float2(wrow[256]);
            float2 wg = __bfloat1622float2(wrow[512]);
            float2 wo = __bfloat1622float2(wrow[768]);
            float ha = h0s[2*k2], hb = h0s[2*k2+1];
            float hc = h1s[2*k2], hd = h1s[2*k2+1];
            ai0 = fmaf(wi.x,ha, fmaf(wi.y,hb, ai0));
            af0 = fmaf(wf.x,ha, fmaf(wf.y,hb, af0));
            ag0 = fmaf(wg.x,ha, fmaf(wg.y,hb, ag0));
            ao0 = fmaf(wo.x,ha, fmaf(wo.y,hb, ao0));
            ai1 = fmaf(wi.x,hc, fmaf(wi.y,hd, ai1));
            af1 = fmaf(wf.x,hc, fmaf(wf.y,hd, af1));
            ag1 = fmaf(wg.x,hc, fmaf(wg.y,hd, ag1));
            ao1 = fmaf(wo.x,hc, fmaf(wo.y,hd, ao1));
        }
        __syncthreads();
        c0 = sigf(af0)*c0 + sigf(ai0)*tanhf(ag0);
        float h0 = sigf(ao0)*tanhf(c0);
        c1 = sigf(af1)*c1 + sigf(ai1)*tanhf(ag1);
        float h1 = sigf(ao1)*tanhf(c1);
        h0s[j] = h0; h1s[j] = h1;
        hall[(size_t)(t*64 + p0)*512 + dir*256 + j] = h0;
        hall[(size_t)(t*64 + p1)*512 + dir*256 + j] = h1;
        __syncthreads();
    }
}

// ---------------------------------------------------------------- uv + p1 + p2 fused
__global__ __launch_bounds__(256) void post_lstm(const float* __restrict__ hall,
                                                 const float* __restrict__ Ws,
                                                 float* __restrict__ u, float* __restrict__ v,
                                                 const float* __restrict__ W1, const float* __restrict__ b1,
                                                 const float* __restrict__ W2, const float* __restrict__ b2,
                                                 float* __restrict__ p1, float* __restrict__ p2) {
    if (blockIdx.x < 512) {
        int bi = blockIdx.x;
        int i  = bi & 63;
        int tid = threadIdx.x;
        float pu = 0.0f, pv = 0.0f;
        for (int q = tid; q < 1536; q += 256) {
            int seg = q >> 9, kk = q & 511;
            float tv = 0.0f;
            if (seg == 0)       tv = hall[(size_t)bi*512 + kk];
            else if (seg == 1)  { if (i > 0)  tv = hall[(size_t)(bi-1)*512 + kk]; }
            else                { if (i < 63) tv = hall[(size_t)(bi+1)*512 + kk]; }
            pu = fmaf(tv, Ws[q],        pu);
            pv = fmaf(tv, Ws[1536 + q], pv);
        }
        for (int off = 32; off; off >>= 1) { pu += __shfl_xor(pu, off); pv += __shfl_xor(pv, off); }
        __shared__ float ru[4], rv[4];
        int wv = tid >> 6, lane = tid & 63;
        if (lane == 0) { ru[wv] = pu; rv[wv] = pv; }
        __syncthreads();
        if (tid == 0) { u[bi] = ru[0]+ru[1]+ru[2]+ru[3]; v[bi] = rv[0]+rv[1]+rv[2]+rv[3]; }
    } else {
        int blk = blockIdx.x - 512;
        int sel = blk >> 6; blk &= 63;
        gemm_body(hall, sel ? W2 : W1, sel ? b2 : b1, sel ? p2 : p1,
                  128, 512, blk & 15, blk >> 4);
    }
}

// ---------------------------------------------------------------- Eisner + row_lse + finalize
// One block per batch, 512 threads (8 waves). One barrier per width.
// Row-access-only LDS tables (stride 65 -> conflict-free row reads):
//   T1: [i][k] (k>=i) = C_r[i][k] ;  [j][k] (k<j) = C_r[k][j]
//   T2: [i][k] (k>=i) = C_l[i][k] ;  [j][k] (k<j) = C_l[k+1][j]
//   T3: [i][k] (k>i)  = I_r[i][k] ;  [j][k] (k<j) = I_l[k][j]
// 4 lanes per span-task; reductions via quad_perm DPP (no ds_swizzle).
__global__ __launch_bounds__(512) void eisner_final(const float* __restrict__ u,
                                                    const float* __restrict__ v,
                                                    const float* __restrict__ bs,
                                                    const float* __restrict__ S,
                                                    const float* __restrict__ prior,
                                                    const int* __restrict__ heads,
                                                    float* __restrict__ out) {
    int b = blockIdx.x;
    __shared__ float T1[64][65];
    __shared__ float T2[64][65];
    __shared__ float T3[64][65];
    __shared__ float su[64], sv[64], lseSb[64];
    int tid = threadIdx.x;
    if (tid < 64) {
        su[tid] = u[b*64 + tid];
        sv[tid] = v[b*64 + tid];
        T1[tid][tid] = 0.0f;               // C_r diag
        T2[tid][tid] = 0.0f;               // C_l diag (row form)
        if (tid >= 1) T2[tid][tid-1] = 0.0f;  // C_l diag (col-shift form)
    }
    float bsv = bs[0];
    // row logsumexp of S straight from global (L2-resident)
    int wvi = tid >> 6, lane = tid & 63;
    for (int r = wvi; r < 64; r += 8) {
        float x = S[(size_t)(b*64 + r)*64 + lane];
        float m = x;
        for (int off = 32; off; off >>= 1) m = fmaxf(m, __shfl_xor(m, off));
        float se = expf(x - m);
        for (int off = 32; off; off >>= 1) se += __shfl_xor(se, off);
        if (lane == 0) lseSb[r] = m + logf(se);
    }
    __syncthreads();
    int q   = tid >> 2;          // 0..127
    int sub = tid & 3;
    bool isL = (q >= 64);
    int i = isL ? (q - 64) : q;  // span start
    for (int w = 1; w < 64; ++w) {
        int ns = 64 - w;
        if (i < ns) {
            int j = i + w;
            const float* t1i = &T1[i][0];
            const float* t2i = &T2[i][0];
            const float* t1j = &T1[j][0];
            const float* t2j = &T2[j][0];
            const float* t3i = &T3[i][0];
            const float* t3j = &T3[j][0];
            // ---- inc = lse_{k=i..j-1} C_r[i][k] + C_l[k+1][j]
            float m1 = -INFINITY;
            for (int k = i + sub; k < j; k += 4) m1 = fmaxf(m1, t1i[k] + t2j[k]);
            m1 = quad_max(m1);
            float s1 = 0.0f;
            for (int k = i + sub; k < j; k += 4) s1 += exp2f((t1i[k] + t2j[k] - m1) * L2E);
            s1 = quad_sum(s1);
            float inc = m1 + log2f(s1) * LN2;
            if (!isL) {
                float Ir = inc + su[i] + sv[j] + bsv;
                // C_r[i][j] = lse( lse_{k=i+1..j-1} I_r[i][k]+C_r[k][j],  Ir )
                float m2 = Ir;
                for (int k = i + 1 + sub; k < j; k += 4) m2 = fmaxf(m2, t3i[k] + t1j[k]);
                m2 = quad_max(m2);
                float s2 = 0.0f;
                for (int k = i + 1 + sub; k < j; k += 4) s2 += exp2f((t3i[k] + t1j[k] - m2) * L2E);
                s2 = quad_sum(s2);
                s2 += exp2f((Ir - m2) * L2E);
                float Cr = m2 + log2f(s2) * LN2;
                if (sub == 0) {
                    T3[i][j] = Ir;      // I_r row form
                    T1[i][j] = Cr;      // C_r row form
                    T1[j][i] = Cr;      // C_r col form
                }
            } else {
                float Il = inc + su[j] + sv[i] + bsv;
                // C_l[i][j] = lse( lse_{k=i+1..j-1} C_l[i][k]+I_l[k][j],  Il )   (k=i term == Il)
                float m2 = Il;
                for (int k = i + 1 + sub; k < j; k += 4) m2 = fmaxf(m2, t2i[k] + t3j[k]);
                m2 = quad_max(m2);
                float s2 = 0.0f;
                for (int k = i + 1 + sub; k < j; k += 4) s2 += exp2f((t2i[k] + t3j[k] - m2) * L2E);
                s2 = quad_sum(s2);
                s2 += exp2f((Il - m2) * L2E);
                float Cl = m2 + log2f(s2) * LN2;
                if (sub == 0) {
                    T3[j][i] = Il;                   // I_l col form
                    T2[i][j] = Cl;                   // C_l row form
                    if (i >= 1) T2[j][i-1] = Cl;     // C_l col-shift form
                }
            }
        }
        __syncthreads();
    }
    // finalize (wave 0)
    if (tid < 64) {
        int m = tid;
        float logZv = T1[0][63];
        float gv = -INFINITY;
        if (m >= 1) {
            int hd = heads[b*64 + m];
            float crf = su[hd] + sv[m] + bsv;
            float rec = S[(size_t)(b*64 + hd)*64 + m] - lseSb[hd];
            gv = crf + rec + prior[(size_t)(b*64 + hd)*64 + m] * (1.0f/64.0f);
        }
        float mm = gv;
        for (int off = 32; off; off >>= 1) mm = fmaxf(mm, __shfl_xor(mm, off));
        float se = (m >= 1) ? expf(gv - mm) : 0.0f;
        for (int off = 32; off; off >>= 1) se += __shfl_xor(se, off);
        if (m == 0) {
            float red = (mm + logf(se)) - logZv;
            atomicAdd(out, -red * 0.125f);
        }
    }
}

// ---------------------------------------------------------------- launch
extern "C" void kernel_launch(void* const* d_in, const int* in_sizes, int n_in,
                              void* d_out, int out_size, void* d_ws, size_t ws_size,
                              hipStream_t stream) {
    const int*   sents = (const int*)  d_in[0];
    const float* mask  = (const float*)d_in[1];
    const float* prior = (const float*)d_in[2];
    const int*   heads = (const int*)  d_in[3];
    const float* emb   = (const float*)d_in[4];
    const float* Wih_f = (const float*)d_in[5];
    const float* Whh_f = (const float*)d_in[6];
    const float* bih_f = (const float*)d_in[7];
    const float* bhh_f = (const float*)d_in[8];
    const float* Wih_b = (const float*)d_in[9];
    const float* Whh_b = (const float*)d_in[10];
    const float* bih_b = (const float*)d_in[11];
    const float* bhh_b = (const float*)d_in[12];
    const float* W1    = (const float*)d_in[13];
    const float* b1    = (const float*)d_in[14];
    const float* W2    = (const float*)d_in[15];
    const float* b2    = (const float*)d_in[16];
    const float* Ws    = (const float*)d_in[17];
    const float* bs    = (const float*)d_in[18];
    float* out = (float*)d_out;

    char* w = (char*)d_ws;
    float* embeds = (float*)(w + 0);                    // 512 KB
    float* gxf    = (float*)(w + 524288);               // 2 MB
    float* gxb    = (float*)(w + 2621440);              // 2 MB
    __hip_bfloat162* wTf = (__hip_bfloat162*)(w + 4718592);  // 512 KB
    __hip_bfloat162* wTb = (__hip_bfloat162*)(w + 5242880);  // 512 KB
    float* biasf  = (float*)(w + 5767168);              // 4 KB
    float* biasb  = (float*)(w + 5771264);              // 4 KB
    float* hall   = (float*)(w + 5775360);              // 1 MB
    float* uArr   = (float*)(w + 6823936);              // 2 KB
    float* vArr   = (float*)(w + 6825984);              // 2 KB
    float* p1     = (float*)(w + 6828032);              // 256 KB
    float* p2     = (float*)(w + 7090176);              // 256 KB
    float* S      = (float*)(w + 7352320);              // 128 KB

    prep_all<<<1536, 256, 0, stream>>>(Whh_f, Whh_b, bih_f, bhh_f, bih_b, bhh_b,
                                       wTf, wTb, biasf, biasb,
                                       sents, mask, emb, embeds, out);
    gemm_ih<<<dim3(16,32,2), 256, 0, stream>>>(embeds, Wih_f, Wih_b, biasf, biasb, gxf, gxb);
    lstm_rec<<<64, 256, 0, stream>>>(gxf, gxb, wTf, wTb, hall);
    post_lstm<<<640, 256, 0, stream>>>(hall, Ws, uArr, vArr, W1, b1, W2, b2, p1, p2);
    gemm32<<<dim3(2,2,8), 256, 0, stream>>>(p1, p2, nullptr, S, 64, 128, 8192, 8192, 4096);
    eisner_final<<<8, 512, 0, stream>>>(uArr, vArr, bs, S, prior, heads, out);
    (void)in_sizes; (void)n_in; (void)out_size; (void)ws_size;
}

// Round 5
// 378.749 us; speedup vs baseline: 1.6009x; 1.1733x over previous
//
#include <hip/hip_runtime.h>
#include <hip/hip_bf16.h>
#include <math.h>

#define L2E 1.44269504f
#define LN2 0.69314718f

__device__ __forceinline__ float sigf(float x){ return 1.0f/(1.0f+expf(-x)); }

// quad (4-lane) reductions via DPP quad_perm — VALU pipe, no LDS latency
__device__ __forceinline__ float quad_max(float x) {
    x = fmaxf(x, __int_as_float(__builtin_amdgcn_mov_dpp(__float_as_int(x), 0xB1, 0xF, 0xF, true)));
    x = fmaxf(x, __int_as_float(__builtin_amdgcn_mov_dpp(__float_as_int(x), 0x4E, 0xF, 0xF, true)));
    return x;
}
__device__ __forceinline__ float quad_sum(float x) {
    x += __int_as_float(__builtin_amdgcn_mov_dpp(__float_as_int(x), 0xB1, 0xF, 0xF, true));
    x += __int_as_float(__builtin_amdgcn_mov_dpp(__float_as_int(x), 0x4E, 0xF, 0xF, true));
    return x;
}

// ---------------------------------------------------------------- prep + embed + out-zero
__global__ __launch_bounds__(256) void prep_all(const float* __restrict__ Whh_f, const float* __restrict__ Whh_b,
                             const float* __restrict__ bih_f, const float* __restrict__ bhh_f,
                             const float* __restrict__ bih_b, const float* __restrict__ bhh_b,
                             __hip_bfloat162* __restrict__ wTf, __hip_bfloat162* __restrict__ wTb,
                             float* __restrict__ biasf, float* __restrict__ biasb,
                             const int* __restrict__ sents, const float* __restrict__ mask,
                             const float* __restrict__ emb, float* __restrict__ embeds,
                             float* __restrict__ out) {
    if (blockIdx.x < 1024) {
        int idx = blockIdx.x * 256 + threadIdx.x;      // 0 .. 262143
        int dir = idx >> 17;
        int r   = idx & 131071;
        int k2  = r >> 10;
        int g   = r & 1023;
        const float* W = dir ? Whh_b : Whh_f;
        __hip_bfloat162 t;
        t.x = __float2bfloat16(W[g*256 + 2*k2]);
        t.y = __float2bfloat16(W[g*256 + 2*k2 + 1]);
        (dir ? wTb : wTf)[r] = t;
        if (idx < 1024)       biasf[idx]      = bih_f[idx]      + bhh_f[idx];
        else if (idx < 2048)  biasb[idx-1024] = bih_b[idx-1024] + bhh_b[idx-1024];
        if (idx == 0) out[0] = 0.0f;
    } else {
        int bl = blockIdx.x - 1024;   // 0..511
        int d  = threadIdx.x;         // 0..255
        const int*   srow = sents + bl*32;
        const float* mrow = mask  + bl*32;
        float acc = 0.0f, el = 0.0f;
        for (int w = 0; w < 32; ++w) {
            float m = mrow[w];
            el  += m;
            acc += emb[(size_t)srow[w]*256 + d] * m;
        }
        float den = el + (el == 0.0f ? 1.0f : 0.0f);
        embeds[bl*256 + d] = acc / den;
    }
}

// ---------------------------------------------------------------- shared GEMM body
__device__ __forceinline__ void gemm_body(const float* __restrict__ A,
                                          const float* __restrict__ Bm,
                                          const float* __restrict__ bias,
                                          float* __restrict__ C,
                                          int N, int K, int bx, int by) {
    __shared__ float As[32][33];   // [k][m]
    __shared__ float Bs[32][33];   // [k][n]
    int tid = threadIdx.x;
    int tx = tid & 15, ty = tid >> 4;
    int row0 = bx * 32, col0 = by * 32;
    float a00=0.f, a01=0.f, a10=0.f, a11=0.f;
    int e = tid * 4;
    int lr = e >> 5, lc = e & 31;
    for (int k0 = 0; k0 < K; k0 += 32) {
        const float* ap = A  + (size_t)(row0+lr)*K + k0 + lc;
        const float* bp = Bm + (size_t)(col0+lr)*K + k0 + lc;
        As[lc  ][lr] = ap[0]; As[lc+1][lr] = ap[1]; As[lc+2][lr] = ap[2]; As[lc+3][lr] = ap[3];
        Bs[lc  ][lr] = bp[0]; Bs[lc+1][lr] = bp[1]; Bs[lc+2][lr] = bp[2]; Bs[lc+3][lr] = bp[3];
        __syncthreads();
        #pragma unroll
        for (int kc = 0; kc < 32; ++kc) {
            float x0 = As[kc][ty*2], x1 = As[kc][ty*2+1];
            float y0 = Bs[kc][tx*2], y1 = Bs[kc][tx*2+1];
            a00 = fmaf(x0,y0,a00); a01 = fmaf(x0,y1,a01);
            a10 = fmaf(x1,y0,a10); a11 = fmaf(x1,y1,a11);
        }
        __syncthreads();
    }
    int rr = row0 + ty*2, cc = col0 + tx*2;
    float b0 = bias ? bias[cc]   : 0.0f;
    float b1 = bias ? bias[cc+1] : 0.0f;
    C[(size_t)rr*N + cc]       = a00 + b0;
    C[(size_t)rr*N + cc + 1]   = a01 + b1;
    C[(size_t)(rr+1)*N + cc]   = a10 + b0;
    C[(size_t)(rr+1)*N + cc+1] = a11 + b1;
}

__global__ __launch_bounds__(256) void gemm_ih(const float* __restrict__ embeds,
                                               const float* __restrict__ Wf, const float* __restrict__ Wb,
                                               const float* __restrict__ biasf, const float* __restrict__ biasb,
                                               float* __restrict__ gxf, float* __restrict__ gxb) {
    int dir = blockIdx.z;
    gemm_body(embeds, dir ? Wb : Wf, dir ? biasb : biasf, dir ? gxb : gxf,
              1024, 256, blockIdx.x, blockIdx.y);
}

__global__ __launch_bounds__(256) void gemm32(const float* __restrict__ A,
                                              const float* __restrict__ Bm,
                                              const float* __restrict__ bias,
                                              float* __restrict__ C,
                                              int N, int K, int sA, int sB, int sC) {
    gemm_body(A + (size_t)blockIdx.z * sA, Bm + (size_t)blockIdx.z * sB, bias,
              C + (size_t)blockIdx.z * sC, N, K, blockIdx.x, blockIdx.y);
}

// ---------------------------------------------------------------- LSTM recurrence
__global__ __launch_bounds__(256) void lstm_rec(const float* __restrict__ gxf,
                                                const float* __restrict__ gxb,
                                                const __hip_bfloat162* __restrict__ wTf,
                                                const __hip_bfloat162* __restrict__ wTb,
                                                float* __restrict__ hall) {
    int blk  = blockIdx.x;        // 0..63
    int dir  = blk >> 5;
    int pair = blk & 31;
    int p0 = pair*2, p1 = p0 + 1;
    int j  = threadIdx.x;         // cell 0..255
    const float* gx = dir ? gxb : gxf;
    const __hip_bfloat162* wT = dir ? wTb : wTf;
    __shared__ float h0s[256], h1s[256];
    h0s[j] = 0.0f; h1s[j] = 0.0f;
    float c0 = 0.0f, c1 = 0.0f;
    __syncthreads();
    for (int s = 0; s < 8; ++s) {
        int t = dir ? (7 - s) : s;
        const float* g0 = gx + (size_t)(t*64 + p0)*1024;
        const float* g1 = gx + (size_t)(t*64 + p1)*1024;
        float ai0 = g0[j], af0 = g0[256+j], ag0 = g0[512+j], ao0 = g0[768+j];
        float ai1 = g1[j], af1 = g1[256+j], ag1 = g1[512+j], ao1 = g1[768+j];
        for (int k2 = 0; k2 < 128; ++k2) {
            const __hip_bfloat162* wrow = wT + k2*1024 + j;
            float2 wi = __bfloat1622float2(wrow[0]);
            float2 wf = __bfloat1622float2(wrow[256]);
            float2 wg = __bfloat1622float2(wrow[512]);
            float2 wo = __bfloat1622float2(wrow[768]);
            float ha = h0s[2*k2], hb = h0s[2*k2+1];
            float hc = h1s[2*k2], hd = h1s[2*k2+1];
            ai0 = fmaf(wi.x,ha, fmaf(wi.y,hb, ai0));
            af0 = fmaf(wf.x,ha, fmaf(wf.y,hb, af0));
            ag0 = fmaf(wg.x,ha, fmaf(wg.y,hb, ag0));
            ao0 = fmaf(wo.x,ha, fmaf(wo.y,hb, ao0));
            ai1 = fmaf(wi.x,hc, fmaf(wi.y,hd, ai1));
            af1 = fmaf(wf.x,hc, fmaf(wf.y,hd, af1));
            ag1 = fmaf(wg.x,hc, fmaf(wg.y,hd, ag1));
            ao1 = fmaf(wo.x,hc, fmaf(wo.y,hd, ao1));
        }
        __syncthreads();
        c0 = sigf(af0)*c0 + sigf(ai0)*tanhf(ag0);
        float h0 = sigf(ao0)*tanhf(c0);
        c1 = sigf(af1)*c1 + sigf(ai1)*tanhf(ag1);
        float h1 = sigf(ao1)*tanhf(c1);
        h0s[j] = h0; h1s[j] = h1;
        hall[(size_t)(t*64 + p0)*512 + dir*256 + j] = h0;
        hall[(size_t)(t*64 + p1)*512 + dir*256 + j] = h1;
        __syncthreads();
    }
}

// ---------------------------------------------------------------- uv + p1 + p2 fused
__global__ __launch_bounds__(256) void post_lstm(const float* __restrict__ hall,
                                                 const float* __restrict__ Ws,
                                                 float* __restrict__ u, float* __restrict__ v,
                                                 const float* __restrict__ W1, const float* __restrict__ b1,
                                                 const float* __restrict__ W2, const float* __restrict__ b2,
                                                 float* __restrict__ p1, float* __restrict__ p2) {
    if (blockIdx.x < 512) {
        int bi = blockIdx.x;
        int i  = bi & 63;
        int tid = threadIdx.x;
        float pu = 0.0f, pv = 0.0f;
        for (int q = tid; q < 1536; q += 256) {
            int seg = q >> 9, kk = q & 511;
            float tv = 0.0f;
            if (seg == 0)       tv = hall[(size_t)bi*512 + kk];
            else if (seg == 1)  { if (i > 0)  tv = hall[(size_t)(bi-1)*512 + kk]; }
            else                { if (i < 63) tv = hall[(size_t)(bi+1)*512 + kk]; }
            pu = fmaf(tv, Ws[q],        pu);
            pv = fmaf(tv, Ws[1536 + q], pv);
        }
        for (int off = 32; off; off >>= 1) { pu += __shfl_xor(pu, off); pv += __shfl_xor(pv, off); }
        __shared__ float ru[4], rv[4];
        int wv = tid >> 6, lane = tid & 63;
        if (lane == 0) { ru[wv] = pu; rv[wv] = pv; }
        __syncthreads();
        if (tid == 0) { u[bi] = ru[0]+ru[1]+ru[2]+ru[3]; v[bi] = rv[0]+rv[1]+rv[2]+rv[3]; }
    } else {
        int blk = blockIdx.x - 512;
        int sel = blk >> 6; blk &= 63;
        gemm_body(hall, sel ? W2 : W1, sel ? b2 : b1, sel ? p2 : p1,
                  128, 512, blk & 15, blk >> 4);
    }
}

// ---------------------------------------------------------------- Eisner + row_lse + finalize
// One block per batch, 512 threads (8 waves). One barrier per width.
// Single LDS arena, stride 68 (16B-aligned rows):
//   T1: [i][k] (k>=i) = C_r[i][k] ;  [j][k] (k<j) = C_r[k][j]
//   T2: [i][k] (k>=i) = C_l[i][k] ;  [j][k] (k<j) = C_l[k+1][j]
//   T3: [i][k] (k>i)  = I_r[i][k] ;  [j][k] (k<j) = I_l[k][j]
// 4 lanes/span-task; ds_read_b128 blocks (k rounded to x4, masked -INF),
// terms retained in registers across max+sum passes; quad_perm DPP reduce.
#define TSTRIDE 68
__global__ __launch_bounds__(512) void eisner_final(const float* __restrict__ u,
                                                    const float* __restrict__ v,
                                                    const float* __restrict__ bs,
                                                    const float* __restrict__ S,
                                                    const float* __restrict__ prior,
                                                    const int* __restrict__ heads,
                                                    float* __restrict__ out) {
    int b = blockIdx.x;
    __shared__ __align__(16) float Tall[3*64*TSTRIDE + 64];   // +64 pad for block overshoot
    __shared__ float su[64], sv[64], lseSb[64];
    float* T1 = &Tall[0];
    float* T2 = &Tall[64*TSTRIDE];
    float* T3 = &Tall[2*64*TSTRIDE];
    int tid = threadIdx.x;
    if (tid < 64) {
        su[tid] = u[b*64 + tid];
        sv[tid] = v[b*64 + tid];
        T1[tid*TSTRIDE + tid] = 0.0f;               // C_r diag
        T2[tid*TSTRIDE + tid] = 0.0f;               // C_l diag (row form)
        if (tid >= 1) T2[tid*TSTRIDE + tid-1] = 0.0f;  // C_l diag (col-shift form)
    }
    float bsv = bs[0];
    // row logsumexp of S straight from global (L2-resident)
    int wvi = tid >> 6, lane = tid & 63;
    for (int r = wvi; r < 64; r += 8) {
        float x = S[(size_t)(b*64 + r)*64 + lane];
        float m = x;
        for (int off = 32; off; off >>= 1) m = fmaxf(m, __shfl_xor(m, off));
        float se = expf(x - m);
        for (int off = 32; off; off >>= 1) se += __shfl_xor(se, off);
        if (lane == 0) lseSb[r] = m + logf(se);
    }
    __syncthreads();
    int q   = tid >> 2;          // 0..127
    int sub = tid & 3;
    bool isL = (q >= 64);
    int i = isL ? (q - 64) : q;  // span start
    for (int w = 1; w < 64; ++w) {
        int ns = 64 - w;
        if (i < ns) {
            int j = i + w;
            const float* t1i = &T1[i*TSTRIDE];
            const float* t2i = &T2[i*TSTRIDE];
            const float* t1j = &T1[j*TSTRIDE];
            const float* t2j = &T2[j*TSTRIDE];
            const float* t3i = &T3[i*TSTRIDE];
            const float* t3j = &T3[j*TSTRIDE];
            // ---- inc = lse_{k=i..j-1} C_r[i][k] + C_l[k+1][j]
            float va[5][4];
            int k0 = i & ~3;
            int nb = (j - k0 + 15) >> 4;
            float m1 = -INFINITY;
            #pragma unroll
            for (int t = 0; t < 5; ++t) {
                if (t >= nb) break;
                int k = k0 + (t << 4) + (sub << 2);
                float4 a = *(const float4*)&t1i[k];
                float4 c = *(const float4*)&t2j[k];
                va[t][0] = (k   >= i && k   < j) ? a.x + c.x : -INFINITY;
                va[t][1] = (k+1 >= i && k+1 < j) ? a.y + c.y : -INFINITY;
                va[t][2] = (k+2 >= i && k+2 < j) ? a.z + c.z : -INFINITY;
                va[t][3] = (k+3 >= i && k+3 < j) ? a.w + c.w : -INFINITY;
                m1 = fmaxf(m1, fmaxf(fmaxf(va[t][0], va[t][1]), fmaxf(va[t][2], va[t][3])));
            }
            m1 = quad_max(m1);
            float s1 = 0.0f;
            #pragma unroll
            for (int t = 0; t < 5; ++t) {
                if (t >= nb) break;
                s1 += exp2f((va[t][0] - m1) * L2E) + exp2f((va[t][1] - m1) * L2E)
                    + exp2f((va[t][2] - m1) * L2E) + exp2f((va[t][3] - m1) * L2E);
            }
            s1 = quad_sum(s1);
            float inc = m1 + log2f(s1) * LN2;
            // ---- C update terms: k in [i+1, j)
            const float* ta = isL ? t2i : t3i;
            const float* tb = isL ? t3j : t1j;
            float Ix = inc + (isL ? (su[j] + sv[i]) : (su[i] + sv[j])) + bsv;
            int k0c = (i + 1) & ~3;
            int nbc = (j - k0c + 15) >> 4;
            if (j <= k0c) nbc = 0;
            float vb[5][4];
            float m2 = -INFINITY;
            #pragma unroll
            for (int t = 0; t < 5; ++t) {
                if (t >= nbc) break;
                int k = k0c + (t << 4) + (sub << 2);
                float4 a = *(const float4*)&ta[k];
                float4 c = *(const float4*)&tb[k];
                vb[t][0] = (k   >= i+1 && k   < j) ? a.x + c.x : -INFINITY;
                vb[t][1] = (k+1 >= i+1 && k+1 < j) ? a.y + c.y : -INFINITY;
                vb[t][2] = (k+2 >= i+1 && k+2 < j) ? a.z + c.z : -INFINITY;
                vb[t][3] = (k+3 >= i+1 && k+3 < j) ? a.w + c.w : -INFINITY;
                m2 = fmaxf(m2, fmaxf(fmaxf(vb[t][0], vb[t][1]), fmaxf(vb[t][2], vb[t][3])));
            }
            m2 = fmaxf(quad_max(m2), Ix);
            float s2 = 0.0f;
            #pragma unroll
            for (int t = 0; t < 5; ++t) {
                if (t >= nbc) break;
                s2 += exp2f((vb[t][0] - m2) * L2E) + exp2f((vb[t][1] - m2) * L2E)
                    + exp2f((vb[t][2] - m2) * L2E) + exp2f((vb[t][3] - m2) * L2E);
            }
            s2 = quad_sum(s2);
            s2 += exp2f((Ix - m2) * L2E);
            float Cx = m2 + log2f(s2) * LN2;
            if (sub == 0) {
                if (!isL) {
                    T3[i*TSTRIDE + j] = Ix;           // I_r row form
                    T1[i*TSTRIDE + j] = Cx;           // C_r row form
                    T1[j*TSTRIDE + i] = Cx;           // C_r col form
                } else {
                    T3[j*TSTRIDE + i] = Ix;           // I_l col form
                    T2[i*TSTRIDE + j] = Cx;           // C_l row form
                    if (i >= 1) T2[j*TSTRIDE + i-1] = Cx;  // C_l col-shift form
                }
            }
        }
        __syncthreads();
    }
    // finalize (wave 0)
    if (tid < 64) {
        int m = tid;
        float logZv = T1[0*TSTRIDE + 63];
        float gv = -INFINITY;
        if (m >= 1) {
            int hd = heads[b*64 + m];
            float crf = su[hd] + sv[m] + bsv;
            float rec = S[(size_t)(b*64 + hd)*64 + m] - lseSb[hd];
            gv = crf + rec + prior[(size_t)(b*64 + hd)*64 + m] * (1.0f/64.0f);
        }
        float mm = gv;
        for (int off = 32; off; off >>= 1) mm = fmaxf(mm, __shfl_xor(mm, off));
        float se = (m >= 1) ? expf(gv - mm) : 0.0f;
        for (int off = 32; off; off >>= 1) se += __shfl_xor(se, off);
        if (m == 0) {
            float red = (mm + logf(se)) - logZv;
            atomicAdd(out, -red * 0.125f);
        }
    }
}

// ---------------------------------------------------------------- launch
extern "C" void kernel_launch(void* const* d_in, const int* in_sizes, int n_in,
                              void* d_out, int out_size, void* d_ws, size_t ws_size,
                              hipStream_t stream) {
    const int*   sents = (const int*)  d_in[0];
    const float* mask  = (const float*)d_in[1];
    const float* prior = (const float*)d_in[2];
    const int*   heads = (const int*)  d_in[3];
    const float* emb   = (const float*)d_in[4];
    const float* Wih_f = (const float*)d_in[5];
    const float* Whh_f = (const float*)d_in[6];
    const float* bih_f = (const float*)d_in[7];
    const float* bhh_f = (const float*)d_in[8];
    const float* Wih_b = (const float*)d_in[9];
    const float* Whh_b = (const float*)d_in[10];
    const float* bih_b = (const float*)d_in[11];
    const float* bhh_b = (const float*)d_in[12];
    const float* W1    = (const float*)d_in[13];
    const float* b1    = (const float*)d_in[14];
    const float* W2    = (const float*)d_in[15];
    const float* b2    = (const float*)d_in[16];
    const float* Ws    = (const float*)d_in[17];
    const float* bs    = (const float*)d_in[18];
    float* out = (float*)d_out;

    char* w = (char*)d_ws;
    float* embeds = (float*)(w + 0);                    // 512 KB
    float* gxf    = (float*)(w + 524288);               // 2 MB
    float* gxb    = (float*)(w + 2621440);              // 2 MB
    __hip_bfloat162* wTf = (__hip_bfloat162*)(w + 4718592);  // 512 KB
    __hip_bfloat162* wTb = (__hip_bfloat162*)(w + 5242880);  // 512 KB
    float* biasf  = (float*)(w + 5767168);              // 4 KB
    float* biasb  = (float*)(w + 5771264);              // 4 KB
    float* hall   = (float*)(w + 5775360);              // 1 MB
    float* uArr   = (float*)(w + 6823936);              // 2 KB
    float* vArr   = (float*)(w + 6825984);              // 2 KB
    float* p1     = (float*)(w + 6828032);              // 256 KB
    float* p2     = (float*)(w + 7090176);              // 256 KB
    float* S      = (float*)(w + 7352320);              // 128 KB

    prep_all<<<1536, 256, 0, stream>>>(Whh_f, Whh_b, bih_f, bhh_f, bih_b, bhh_b,
                                       wTf, wTb, biasf, biasb,
                                       sents, mask, emb, embeds, out);
    gemm_ih<<<dim3(16,32,2), 256, 0, stream>>>(embeds, Wih_f, Wih_b, biasf, biasb, gxf, gxb);
    lstm_rec<<<64, 256, 0, stream>>>(gxf, gxb, wTf, wTb, hall);
    post_lstm<<<640, 256, 0, stream>>>(hall, Ws, uArr, vArr, W1, b1, W2, b2, p1, p2);
    gemm32<<<dim3(2,2,8), 256, 0, stream>>>(p1, p2, nullptr, S, 64, 128, 8192, 8192, 4096);
    eisner_final<<<8, 512, 0, stream>>>(uArr, vArr, bs, S, prior, heads, out);
    (void)in_sizes; (void)n_in; (void)out_size; (void)ws_size;
}

// Round 6
// 334.061 us; speedup vs baseline: 1.8151x; 1.1338x over previous
//
#include <hip/hip_runtime.h>
#include <hip/hip_bf16.h>
#include <math.h>

#define L2E 1.44269504f
#define LN2 0.69314718f

__device__ __forceinline__ float sigf(float x){ return 1.0f/(1.0f+expf(-x)); }

// quad (4-lane) reductions via DPP quad_perm — VALU pipe, no LDS latency
__device__ __forceinline__ float quad_max(float x) {
    x = fmaxf(x, __int_as_float(__builtin_amdgcn_mov_dpp(__float_as_int(x), 0xB1, 0xF, 0xF, true)));
    x = fmaxf(x, __int_as_float(__builtin_amdgcn_mov_dpp(__float_as_int(x), 0x4E, 0xF, 0xF, true)));
    return x;
}
__device__ __forceinline__ float quad_sum(float x) {
    x += __int_as_float(__builtin_amdgcn_mov_dpp(__float_as_int(x), 0xB1, 0xF, 0xF, true));
    x += __int_as_float(__builtin_amdgcn_mov_dpp(__float_as_int(x), 0x4E, 0xF, 0xF, true));
    return x;
}

// ---------------------------------------------------------------- prep + embed + out-zero
// Whh packed as 16B quads: wT[k2*1024 + j*4 + gate] = bf162(W[gate*256+j][2k2], [2k2+1])
// so lstm_rec loads ONE dwordx4 per (k2, cell j).
__global__ __launch_bounds__(256) void prep_all(const float* __restrict__ Whh_f, const float* __restrict__ Whh_b,
                             const float* __restrict__ bih_f, const float* __restrict__ bhh_f,
                             const float* __restrict__ bih_b, const float* __restrict__ bhh_b,
                             __hip_bfloat162* __restrict__ wTf, __hip_bfloat162* __restrict__ wTb,
                             float* __restrict__ biasf, float* __restrict__ biasb,
                             const int* __restrict__ sents, const float* __restrict__ mask,
                             const float* __restrict__ emb, float* __restrict__ embeds,
                             float* __restrict__ out) {
    if (blockIdx.x < 1024) {
        int idx = blockIdx.x * 256 + threadIdx.x;      // 0 .. 262143
        int dir = idx >> 17;
        int r   = idx & 131071;
        int k2  = r >> 10;
        int rem = r & 1023;
        int j   = rem >> 2;      // cell
        int qg  = rem & 3;       // gate (i,f,g,o)
        const float* W = dir ? Whh_b : Whh_f;
        int row = qg * 256 + j;
        __hip_bfloat162 t;
        t.x = __float2bfloat16(W[row*256 + 2*k2]);
        t.y = __float2bfloat16(W[row*256 + 2*k2 + 1]);
        (dir ? wTb : wTf)[r] = t;
        if (idx < 1024)       biasf[idx]      = bih_f[idx]      + bhh_f[idx];
        else if (idx < 2048)  biasb[idx-1024] = bih_b[idx-1024] + bhh_b[idx-1024];
        if (idx == 0) out[0] = 0.0f;
    } else {
        int bl = blockIdx.x - 1024;   // 0..511
        int d  = threadIdx.x;         // 0..255
        const int*   srow = sents + bl*32;
        const float* mrow = mask  + bl*32;
        float acc = 0.0f, el = 0.0f;
        for (int w = 0; w < 32; ++w) {
            float m = mrow[w];
            el  += m;
            acc += emb[(size_t)srow[w]*256 + d] * m;
        }
        float den = el + (el == 0.0f ? 1.0f : 0.0f);
        embeds[bl*256 + d] = acc / den;
    }
}

// ---------------------------------------------------------------- shared GEMM body
__device__ __forceinline__ void gemm_body(const float* __restrict__ A,
                                          const float* __restrict__ Bm,
                                          const float* __restrict__ bias,
                                          float* __restrict__ C,
                                          int N, int K, int bx, int by) {
    __shared__ float As[32][33];   // [k][m]
    __shared__ float Bs[32][33];   // [k][n]
    int tid = threadIdx.x;
    int tx = tid & 15, ty = tid >> 4;
    int row0 = bx * 32, col0 = by * 32;
    float a00=0.f, a01=0.f, a10=0.f, a11=0.f;
    int e = tid * 4;
    int lr = e >> 5, lc = e & 31;
    for (int k0 = 0; k0 < K; k0 += 32) {
        const float* ap = A  + (size_t)(row0+lr)*K + k0 + lc;
        const float* bp = Bm + (size_t)(col0+lr)*K + k0 + lc;
        As[lc  ][lr] = ap[0]; As[lc+1][lr] = ap[1]; As[lc+2][lr] = ap[2]; As[lc+3][lr] = ap[3];
        Bs[lc  ][lr] = bp[0]; Bs[lc+1][lr] = bp[1]; Bs[lc+2][lr] = bp[2]; Bs[lc+3][lr] = bp[3];
        __syncthreads();
        #pragma unroll
        for (int kc = 0; kc < 32; ++kc) {
            float x0 = As[kc][ty*2], x1 = As[kc][ty*2+1];
            float y0 = Bs[kc][tx*2], y1 = Bs[kc][tx*2+1];
            a00 = fmaf(x0,y0,a00); a01 = fmaf(x0,y1,a01);
            a10 = fmaf(x1,y0,a10); a11 = fmaf(x1,y1,a11);
        }
        __syncthreads();
    }
    int rr = row0 + ty*2, cc = col0 + tx*2;
    float b0 = bias ? bias[cc]   : 0.0f;
    float b1 = bias ? bias[cc+1] : 0.0f;
    C[(size_t)rr*N + cc]       = a00 + b0;
    C[(size_t)rr*N + cc + 1]   = a01 + b1;
    C[(size_t)(rr+1)*N + cc]   = a10 + b0;
    C[(size_t)(rr+1)*N + cc+1] = a11 + b1;
}

__global__ __launch_bounds__(256) void gemm_ih(const float* __restrict__ embeds,
                                               const float* __restrict__ Wf, const float* __restrict__ Wb,
                                               const float* __restrict__ biasf, const float* __restrict__ biasb,
                                               float* __restrict__ gxf, float* __restrict__ gxb) {
    int dir = blockIdx.z;
    gemm_body(embeds, dir ? Wb : Wf, dir ? biasb : biasf, dir ? gxb : gxf,
              1024, 256, blockIdx.x, blockIdx.y);
}

__global__ __launch_bounds__(256) void gemm32(const float* __restrict__ A,
                                              const float* __restrict__ Bm,
                                              const float* __restrict__ bias,
                                              float* __restrict__ C,
                                              int N, int K, int sA, int sB, int sC) {
    gemm_body(A + (size_t)blockIdx.z * sA, Bm + (size_t)blockIdx.z * sB, bias,
              C + (size_t)blockIdx.z * sC, N, K, blockIdx.x, blockIdx.y);
}

// ---------------------------------------------------------------- LSTM recurrence
// 16B weight quads (i,f,g,o bf16 pairs) -> one dwordx4 per (k2, cell).
// unroll 8 keeps ~8 loads in flight per thread; h read as float2 from LDS.
__global__ __launch_bounds__(256) void lstm_rec(const float* __restrict__ gxf,
                                                const float* __restrict__ gxb,
                                                const __hip_bfloat162* __restrict__ wTf,
                                                const __hip_bfloat162* __restrict__ wTb,
                                                float* __restrict__ hall) {
    int blk  = blockIdx.x;        // 0..63
    int dir  = blk >> 5;
    int pair = blk & 31;
    int p0 = pair*2, p1 = p0 + 1;
    int j  = threadIdx.x;         // cell 0..255
    const float* gx = dir ? gxb : gxf;
    const float4* wT4 = (const float4*)(dir ? wTb : wTf);
    __shared__ float h0s[256], h1s[256];
    h0s[j] = 0.0f; h1s[j] = 0.0f;
    float c0 = 0.0f, c1 = 0.0f;
    __syncthreads();
    for (int s = 0; s < 8; ++s) {
        int t = dir ? (7 - s) : s;
        const float* g0 = gx + (size_t)(t*64 + p0)*1024;
        const float* g1 = gx + (size_t)(t*64 + p1)*1024;
        float ai0 = g0[j], af0 = g0[256+j], ag0 = g0[512+j], ao0 = g0[768+j];
        float ai1 = g1[j], af1 = g1[256+j], ag1 = g1[512+j], ao1 = g1[768+j];
        #pragma unroll 8
        for (int k2 = 0; k2 < 128; ++k2) {
            float4 wq = wT4[(k2 << 8) + j];
            unsigned int bi_ = __float_as_uint(wq.x);
            unsigned int bf_ = __float_as_uint(wq.y);
            unsigned int bg_ = __float_as_uint(wq.z);
            unsigned int bo_ = __float_as_uint(wq.w);
            float wix = __uint_as_float(bi_ << 16), wiy = __uint_as_float(bi_ & 0xffff0000u);
            float wfx = __uint_as_float(bf_ << 16), wfy = __uint_as_float(bf_ & 0xffff0000u);
            float wgx = __uint_as_float(bg_ << 16), wgy = __uint_as_float(bg_ & 0xffff0000u);
            float wox = __uint_as_float(bo_ << 16), woy = __uint_as_float(bo_ & 0xffff0000u);
            float2 h0p = *(const float2*)&h0s[2*k2];
            float2 h1p = *(const float2*)&h1s[2*k2];
            ai0 = fmaf(wix,h0p.x, fmaf(wiy,h0p.y, ai0));
            af0 = fmaf(wfx,h0p.x, fmaf(wfy,h0p.y, af0));
            ag0 = fmaf(wgx,h0p.x, fmaf(wgy,h0p.y, ag0));
            ao0 = fmaf(wox,h0p.x, fmaf(woy,h0p.y, ao0));
            ai1 = fmaf(wix,h1p.x, fmaf(wiy,h1p.y, ai1));
            af1 = fmaf(wfx,h1p.x, fmaf(wfy,h1p.y, af1));
            ag1 = fmaf(wgx,h1p.x, fmaf(wgy,h1p.y, ag1));
            ao1 = fmaf(wox,h1p.x, fmaf(woy,h1p.y, ao1));
        }
        __syncthreads();
        c0 = sigf(af0)*c0 + sigf(ai0)*tanhf(ag0);
        float h0 = sigf(ao0)*tanhf(c0);
        c1 = sigf(af1)*c1 + sigf(ai1)*tanhf(ag1);
        float h1 = sigf(ao1)*tanhf(c1);
        h0s[j] = h0; h1s[j] = h1;
        hall[(size_t)(t*64 + p0)*512 + dir*256 + j] = h0;
        hall[(size_t)(t*64 + p1)*512 + dir*256 + j] = h1;
        __syncthreads();
    }
}

// ---------------------------------------------------------------- uv + p1 + p2 fused
__global__ __launch_bounds__(256) void post_lstm(const float* __restrict__ hall,
                                                 const float* __restrict__ Ws,
                                                 float* __restrict__ u, float* __restrict__ v,
                                                 const float* __restrict__ W1, const float* __restrict__ b1,
                                                 const float* __restrict__ W2, const float* __restrict__ b2,
                                                 float* __restrict__ p1, float* __restrict__ p2) {
    if (blockIdx.x < 512) {
        int bi = blockIdx.x;
        int i  = bi & 63;
        int tid = threadIdx.x;
        float pu = 0.0f, pv = 0.0f;
        for (int q = tid; q < 1536; q += 256) {
            int seg = q >> 9, kk = q & 511;
            float tv = 0.0f;
            if (seg == 0)       tv = hall[(size_t)bi*512 + kk];
            else if (seg == 1)  { if (i > 0)  tv = hall[(size_t)(bi-1)*512 + kk]; }
            else                { if (i < 63) tv = hall[(size_t)(bi+1)*512 + kk]; }
            pu = fmaf(tv, Ws[q],        pu);
            pv = fmaf(tv, Ws[1536 + q], pv);
        }
        for (int off = 32; off; off >>= 1) { pu += __shfl_xor(pu, off); pv += __shfl_xor(pv, off); }
        __shared__ float ru[4], rv[4];
        int wv = tid >> 6, lane = tid & 63;
        if (lane == 0) { ru[wv] = pu; rv[wv] = pv; }
        __syncthreads();
        if (tid == 0) { u[bi] = ru[0]+ru[1]+ru[2]+ru[3]; v[bi] = rv[0]+rv[1]+rv[2]+rv[3]; }
    } else {
        int blk = blockIdx.x - 512;
        int sel = blk >> 6; blk &= 63;
        gemm_body(hall, sel ? W2 : W1, sel ? b2 : b1, sel ? p2 : p1,
                  128, 512, blk & 15, blk >> 4);
    }
}

// ---------------------------------------------------------------- Eisner + row_lse + finalize
#define TSTRIDE 68
__global__ __launch_bounds__(512) void eisner_final(const float* __restrict__ u,
                                                    const float* __restrict__ v,
                                                    const float* __restrict__ bs,
                                                    const float* __restrict__ S,
                                                    const float* __restrict__ prior,
                                                    const int* __restrict__ heads,
                                                    float* __restrict__ out) {
    int b = blockIdx.x;
    __shared__ __align__(16) float Tall[3*64*TSTRIDE + 64];   // +64 pad for block overshoot
    __shared__ float su[64], sv[64], lseSb[64];
    float* T1 = &Tall[0];
    float* T2 = &Tall[64*TSTRIDE];
    float* T3 = &Tall[2*64*TSTRIDE];
    int tid = threadIdx.x;
    if (tid < 64) {
        su[tid] = u[b*64 + tid];
        sv[tid] = v[b*64 + tid];
        T1[tid*TSTRIDE + tid] = 0.0f;               // C_r diag
        T2[tid*TSTRIDE + tid] = 0.0f;               // C_l diag (row form)
        if (tid >= 1) T2[tid*TSTRIDE + tid-1] = 0.0f;  // C_l diag (col-shift form)
    }
    float bsv = bs[0];
    int wvi = tid >> 6, lane = tid & 63;
    for (int r = wvi; r < 64; r += 8) {
        float x = S[(size_t)(b*64 + r)*64 + lane];
        float m = x;
        for (int off = 32; off; off >>= 1) m = fmaxf(m, __shfl_xor(m, off));
        float se = expf(x - m);
        for (int off = 32; off; off >>= 1) se += __shfl_xor(se, off);
        if (lane == 0) lseSb[r] = m + logf(se);
    }
    __syncthreads();
    int q   = tid >> 2;          // 0..127
    int sub = tid & 3;
    bool isL = (q >= 64);
    int i = isL ? (q - 64) : q;  // span start
    for (int w = 1; w < 64; ++w) {
        int ns = 64 - w;
        if (i < ns) {
            int j = i + w;
            const float* t1i = &T1[i*TSTRIDE];
            const float* t2i = &T2[i*TSTRIDE];
            const float* t1j = &T1[j*TSTRIDE];
            const float* t2j = &T2[j*TSTRIDE];
            const float* t3i = &T3[i*TSTRIDE];
            const float* t3j = &T3[j*TSTRIDE];
            // ---- inc = lse_{k=i..j-1} C_r[i][k] + C_l[k+1][j]
            float va[5][4];
            int k0 = i & ~3;
            int nb = (j - k0 + 15) >> 4;
            float m1 = -INFINITY;
            #pragma unroll
            for (int t = 0; t < 5; ++t) {
                if (t >= nb) break;
                int k = k0 + (t << 4) + (sub << 2);
                float4 a = *(const float4*)&t1i[k];
                float4 c = *(const float4*)&t2j[k];
                va[t][0] = (k   >= i && k   < j) ? a.x + c.x : -INFINITY;
                va[t][1] = (k+1 >= i && k+1 < j) ? a.y + c.y : -INFINITY;
                va[t][2] = (k+2 >= i && k+2 < j) ? a.z + c.z : -INFINITY;
                va[t][3] = (k+3 >= i && k+3 < j) ? a.w + c.w : -INFINITY;
                m1 = fmaxf(m1, fmaxf(fmaxf(va[t][0], va[t][1]), fmaxf(va[t][2], va[t][3])));
            }
            m1 = quad_max(m1);
            float s1 = 0.0f;
            #pragma unroll
            for (int t = 0; t < 5; ++t) {
                if (t >= nb) break;
                s1 += exp2f((va[t][0] - m1) * L2E) + exp2f((va[t][1] - m1) * L2E)
                    + exp2f((va[t][2] - m1) * L2E) + exp2f((va[t][3] - m1) * L2E);
            }
            s1 = quad_sum(s1);
            float inc = m1 + log2f(s1) * LN2;
            // ---- C update terms: k in [i+1, j)
            const float* ta = isL ? t2i : t3i;
            const float* tb = isL ? t3j : t1j;
            float Ix = inc + (isL ? (su[j] + sv[i]) : (su[i] + sv[j])) + bsv;
            int k0c = (i + 1) & ~3;
            int nbc = (j - k0c + 15) >> 4;
            if (j <= k0c) nbc = 0;
            float vb[5][4];
            float m2 = -INFINITY;
            #pragma unroll
            for (int t = 0; t < 5; ++t) {
                if (t >= nbc) break;
                int k = k0c + (t << 4) + (sub << 2);
                float4 a = *(const float4*)&ta[k];
                float4 c = *(const float4*)&tb[k];
                vb[t][0] = (k   >= i+1 && k   < j) ? a.x + c.x : -INFINITY;
                vb[t][1] = (k+1 >= i+1 && k+1 < j) ? a.y + c.y : -INFINITY;
                vb[t][2] = (k+2 >= i+1 && k+2 < j) ? a.z + c.z : -INFINITY;
                vb[t][3] = (k+3 >= i+1 && k+3 < j) ? a.w + c.w : -INFINITY;
                m2 = fmaxf(m2, fmaxf(fmaxf(vb[t][0], vb[t][1]), fmaxf(vb[t][2], vb[t][3])));
            }
            m2 = fmaxf(quad_max(m2), Ix);
            float s2 = 0.0f;
            #pragma unroll
            for (int t = 0; t < 5; ++t) {
                if (t >= nbc) break;
                s2 += exp2f((vb[t][0] - m2) * L2E) + exp2f((vb[t][1] - m2) * L2E)
                    + exp2f((vb[t][2] - m2) * L2E) + exp2f((vb[t][3] - m2) * L2E);
            }
            s2 = quad_sum(s2);
            s2 += exp2f((Ix - m2) * L2E);
            float Cx = m2 + log2f(s2) * LN2;
            if (sub == 0) {
                if (!isL) {
                    T3[i*TSTRIDE + j] = Ix;           // I_r row form
                    T1[i*TSTRIDE + j] = Cx;           // C_r row form
                    T1[j*TSTRIDE + i] = Cx;           // C_r col form
                } else {
                    T3[j*TSTRIDE + i] = Ix;           // I_l col form
                    T2[i*TSTRIDE + j] = Cx;           // C_l row form
                    if (i >= 1) T2[j*TSTRIDE + i-1] = Cx;  // C_l col-shift form
                }
            }
        }
        __syncthreads();
    }
    // finalize (wave 0)
    if (tid < 64) {
        int m = tid;
        float logZv = T1[0*TSTRIDE + 63];
        float gv = -INFINITY;
        if (m >= 1) {
            int hd = heads[b*64 + m];
            float crf = su[hd] + sv[m] + bsv;
            float rec = S[(size_t)(b*64 + hd)*64 + m] - lseSb[hd];
            gv = crf + rec + prior[(size_t)(b*64 + hd)*64 + m] * (1.0f/64.0f);
        }
        float mm = gv;
        for (int off = 32; off; off >>= 1) mm = fmaxf(mm, __shfl_xor(mm, off));
        float se = (m >= 1) ? expf(gv - mm) : 0.0f;
        for (int off = 32; off; off >>= 1) se += __shfl_xor(se, off);
        if (m == 0) {
            float red = (mm + logf(se)) - logZv;
            atomicAdd(out, -red * 0.125f);
        }
    }
}

// ---------------------------------------------------------------- launch
extern "C" void kernel_launch(void* const* d_in, const int* in_sizes, int n_in,
                              void* d_out, int out_size, void* d_ws, size_t ws_size,
                              hipStream_t stream) {
    const int*   sents = (const int*)  d_in[0];
    const float* mask  = (const float*)d_in[1];
    const float* prior = (const float*)d_in[2];
    const int*   heads = (const int*)  d_in[3];
    const float* emb   = (const float*)d_in[4];
    const float* Wih_f = (const float*)d_in[5];
    const float* Whh_f = (const float*)d_in[6];
    const float* bih_f = (const float*)d_in[7];
    const float* bhh_f = (const float*)d_in[8];
    const float* Wih_b = (const float*)d_in[9];
    const float* Whh_b = (const float*)d_in[10];
    const float* bih_b = (const float*)d_in[11];
    const float* bhh_b = (const float*)d_in[12];
    const float* W1    = (const float*)d_in[13];
    const float* b1    = (const float*)d_in[14];
    const float* W2    = (const float*)d_in[15];
    const float* b2    = (const float*)d_in[16];
    const float* Ws    = (const float*)d_in[17];
    const float* bs    = (const float*)d_in[18];
    float* out = (float*)d_out;

    char* w = (char*)d_ws;
    float* embeds = (float*)(w + 0);                    // 512 KB
    float* gxf    = (float*)(w + 524288);               // 2 MB
    float* gxb    = (float*)(w + 2621440);              // 2 MB
    __hip_bfloat162* wTf = (__hip_bfloat162*)(w + 4718592);  // 512 KB
    __hip_bfloat162* wTb = (__hip_bfloat162*)(w + 5242880);  // 512 KB
    float* biasf  = (float*)(w + 5767168);              // 4 KB
    float* biasb  = (float*)(w + 5771264);              // 4 KB
    float* hall   = (float*)(w + 5775360);              // 1 MB
    float* uArr   = (float*)(w + 6823936);              // 2 KB
    float* vArr   = (float*)(w + 6825984);              // 2 KB
    float* p1     = (float*)(w + 6828032);              // 256 KB
    float* p2     = (float*)(w + 7090176);              // 256 KB
    float* S      = (float*)(w + 7352320);              // 128 KB

    prep_all<<<1536, 256, 0, stream>>>(Whh_f, Whh_b, bih_f, bhh_f, bih_b, bhh_b,
                                       wTf, wTb, biasf, biasb,
                                       sents, mask, emb, embeds, out);
    gemm_ih<<<dim3(16,32,2), 256, 0, stream>>>(embeds, Wih_f, Wih_b, biasf, biasb, gxf, gxb);
    lstm_rec<<<64, 256, 0, stream>>>(gxf, gxb, wTf, wTb, hall);
    post_lstm<<<640, 256, 0, stream>>>(hall, Ws, uArr, vArr, W1, b1, W2, b2, p1, p2);
    gemm32<<<dim3(2,2,8), 256, 0, stream>>>(p1, p2, nullptr, S, 64, 128, 8192, 8192, 4096);
    eisner_final<<<8, 512, 0, stream>>>(uArr, vArr, bs, S, prior, heads, out);
    (void)in_sizes; (void)n_in; (void)out_size; (void)ws_size;
}